// Round 9
// baseline (877.579 us; speedup 1.0000x reference)
//
#include <hip/hip_runtime.h>
#include <math.h>

// ---------------------------------------------------------------------------
// EdgeClassifier: 2x SAGEConv(mean) -> per-node MLP -> edge scorer
//  * layer-1 agg: mean commutes with projection -> aggregate raw nf (4-dim),
//    fused with h1 compute (aggh1f_k), h1 stored packed bf16
//  * CSR: 1 atomic pass (rank) + scan + atomic-free scatter fill
//  * gatherh1: 16 gather rows in flight; aggh1 stored packed bf16
//  * node_mlp_k: h1/aggh1(bf16) -> h2 -> hn -> bf16 ST in LDS
//  * edge_k: CSR order, 4 edges/wave x 16 lanes x 4 j; per-quarter broadcast
//    ef loads (no readlane/cndmask); DPP 16-lane reductions; 128-thr blocks
// ---------------------------------------------------------------------------

__device__ __forceinline__ float fast_tanh(float x) {
    x = fminf(fmaxf(x, -15.f), 15.f);
    float e2 = __expf(2.f * x);
    return (e2 - 1.f) * __builtin_amdgcn_rcpf(e2 + 1.f);
}
__device__ __forceinline__ float fast_sigmoid(float x) {
    x = fminf(fmaxf(x, -60.f), 60.f);
    return __builtin_amdgcn_rcpf(1.f + __expf(-x));
}
__device__ __forceinline__ unsigned short f2bf(float f) {   // RNE
    unsigned u = __float_as_uint(f);
    u = u + 0x7FFFu + ((u >> 16) & 1u);
    return (unsigned short)(u >> 16);
}
__device__ __forceinline__ unsigned pack2bf(float lo, float hi) {
    return ((unsigned)f2bf(hi) << 16) | (unsigned)f2bf(lo);
}
__device__ __forceinline__ float bflo(unsigned u) { return __uint_as_float(u << 16); }
__device__ __forceinline__ float bfhi(unsigned u) { return __uint_as_float(u & 0xFFFF0000u); }

// 16-lane all-reduce sum, pure DPP (no LDS/DS)
__device__ __forceinline__ float dpp_sum16(float x) {
    int t;
    t = __builtin_amdgcn_update_dpp(0, __float_as_int(x), 0xB1, 0xF, 0xF, true);  // quad_perm(1,0,3,2)
    x += __int_as_float(t);
    t = __builtin_amdgcn_update_dpp(0, __float_as_int(x), 0x4E, 0xF, 0xF, true);  // quad_perm(2,3,0,1)
    x += __int_as_float(t);
    t = __builtin_amdgcn_update_dpp(0, __float_as_int(x), 0x141, 0xF, 0xF, true); // row_half_mirror
    x += __int_as_float(t);
    t = __builtin_amdgcn_update_dpp(0, __float_as_int(x), 0x140, 0xF, 0xF, true); // row_mirror
    x += __int_as_float(t);
    return x;
}

// rank[e] = arrival index among edges sharing dst; deg accumulates counts
__global__ void rank_k(const int* __restrict__ dst, int* __restrict__ deg,
                       int* __restrict__ rank, int E) {
    int e = blockIdx.x * blockDim.x + threadIdx.x;
    if (e < E) rank[e] = atomicAdd(&deg[dst[e]], 1);
}

__global__ void scan1_k(const int* __restrict__ deg, int* __restrict__ off,
                        int* __restrict__ bsum, int N) {
    __shared__ int tmp[256];
    int i = blockIdx.x * 256 + threadIdx.x;
    int v = (i < N) ? deg[i] : 0;
    tmp[threadIdx.x] = v;
    __syncthreads();
#pragma unroll
    for (int s = 1; s < 256; s <<= 1) {
        int t = (threadIdx.x >= s) ? tmp[threadIdx.x - s] : 0;
        __syncthreads();
        tmp[threadIdx.x] += t;
        __syncthreads();
    }
    if (i < N) off[i] = tmp[threadIdx.x] - v;
    if (threadIdx.x == 255) bsum[blockIdx.x] = tmp[255];
}

__global__ void scan2_k(int* __restrict__ bsum, int nb) {
    __shared__ int tmp[512];
    int i = threadIdx.x;
    int v = (i < nb) ? bsum[i] : 0;
    tmp[i] = v;
    __syncthreads();
#pragma unroll
    for (int s = 1; s < 512; s <<= 1) {
        int t = (i >= s) ? tmp[i - s] : 0;
        __syncthreads();
        tmp[i] += t;
        __syncthreads();
    }
    if (i < nb) bsum[i] = tmp[i] - v;
}

__global__ void scan3_k(int* __restrict__ off, const int* __restrict__ bsum,
                        int N, int E) {
    int i = blockIdx.x * 256 + threadIdx.x;
    if (i < N) off[i] += bsum[blockIdx.x];
    if (i == 0) off[N] = E;
}

// atomic-free CSR fill using precomputed ranks
__global__ void fill2_k(const int* __restrict__ src, const int* __restrict__ dst,
                        const int* __restrict__ off, const int* __restrict__ rank,
                        int2* __restrict__ csr, int E) {
    int e = blockIdx.x * blockDim.x + threadIdx.x;
    if (e >= E) return;
    csr[off[dst[e]] + rank[e]] = make_int2(src[e], e);
}

// one wave per node: aggnf = mean of nf[neighbors] (butterfly), then
// h1[j] = relu(nf@W1s + aggnf@W1n + b1)[j] per lane, stored as bf16
__global__ __launch_bounds__(256, 8)
void aggh1f_k(const int* __restrict__ off, const int2* __restrict__ csr,
              const float* __restrict__ nf,
              const float* __restrict__ W1s, const float* __restrict__ W1n,
              const float* __restrict__ b1, unsigned short* __restrict__ h1s, int N) {
    int n = blockIdx.x * 4 + (threadIdx.x >> 6);
    if (n >= N) return;
    int l = threadIdx.x & 63;
    int s0 = off[n], s1 = off[n + 1];
    float4 a = {0.f, 0.f, 0.f, 0.f};
    for (int i = s0 + l; i < s1; i += 64) {
        float4 r = ((const float4*)nf)[csr[i].x];
        a.x += r.x; a.y += r.y; a.z += r.z; a.w += r.w;
    }
#pragma unroll
    for (int m = 1; m < 64; m <<= 1) {
        a.x += __shfl_xor(a.x, m);
        a.y += __shfl_xor(a.y, m);
        a.z += __shfl_xor(a.z, m);
        a.w += __shfl_xor(a.w, m);
    }
    float invd = 1.f / fmaxf((float)(s1 - s0), 1.f);
    a.x *= invd; a.y *= invd; a.z *= invd; a.w *= invd;
    float4 r = ((const float4*)nf)[n];
    float v = b1[l]
            + r.x * W1s[l] + r.y * W1s[64 + l] + r.z * W1s[128 + l] + r.w * W1s[192 + l]
            + a.x * W1n[l] + a.y * W1n[64 + l] + a.z * W1n[128 + l] + a.w * W1n[192 + l];
    h1s[(size_t)n * 64 + l] = f2bf(fmaxf(v, 0.f));
}

// one wave per node (2 nodes/block): aggh1b[n] = mean of bf16 h1 rows,
// stored packed bf16. 16 gather rows in flight.
__global__ __launch_bounds__(128, 8)
void gatherh1_k(const int* __restrict__ off, const int2* __restrict__ csr,
                const unsigned* __restrict__ h1b, unsigned* __restrict__ ah1b, int N) {
    int n = blockIdx.x * 2 + (threadIdx.x >> 6);
    if (n >= N) return;
    int l = threadIdx.x & 63;
    int g = l >> 4, q = l & 15;
    int s0 = off[n], s1 = off[n + 1];
    float4 acc = {0.f, 0.f, 0.f, 0.f};
    int i = s0;
    for (; i + 16 <= s1; i += 16) {
        int r0 = csr[i + g].x;
        int r1 = csr[i + 4 + g].x;
        int r2 = csr[i + 8 + g].x;
        int r3 = csr[i + 12 + g].x;
        uint2 v0 = *(const uint2*)&h1b[(size_t)r0 * 32 + q * 2];
        uint2 v1 = *(const uint2*)&h1b[(size_t)r1 * 32 + q * 2];
        uint2 v2 = *(const uint2*)&h1b[(size_t)r2 * 32 + q * 2];
        uint2 v3 = *(const uint2*)&h1b[(size_t)r3 * 32 + q * 2];
        acc.x += (bflo(v0.x) + bflo(v1.x)) + (bflo(v2.x) + bflo(v3.x));
        acc.y += (bfhi(v0.x) + bfhi(v1.x)) + (bfhi(v2.x) + bfhi(v3.x));
        acc.z += (bflo(v0.y) + bflo(v1.y)) + (bflo(v2.y) + bflo(v3.y));
        acc.w += (bfhi(v0.y) + bfhi(v1.y)) + (bfhi(v2.y) + bfhi(v3.y));
    }
    for (; i + 4 <= s1; i += 4) {
        int r0 = csr[i + g].x;
        uint2 v0 = *(const uint2*)&h1b[(size_t)r0 * 32 + q * 2];
        acc.x += bflo(v0.x); acc.y += bfhi(v0.x);
        acc.z += bflo(v0.y); acc.w += bfhi(v0.y);
    }
    int rem = s1 - i;
    if (g < rem) {
        int r0 = csr[i + g].x;
        uint2 v0 = *(const uint2*)&h1b[(size_t)r0 * 32 + q * 2];
        acc.x += bflo(v0.x); acc.y += bfhi(v0.x);
        acc.z += bflo(v0.y); acc.w += bfhi(v0.y);
    }
#pragma unroll
    for (int m = 16; m <= 32; m <<= 1) {
        acc.x += __shfl_xor(acc.x, m);
        acc.y += __shfl_xor(acc.y, m);
        acc.z += __shfl_xor(acc.z, m);
        acc.w += __shfl_xor(acc.w, m);
    }
    if (l < 16) {
        float invd = 1.f / fmaxf((float)(s1 - s0), 1.f);
        uint2 pk;
        pk.x = pack2bf(acc.x * invd, acc.y * invd);
        pk.y = pack2bf(acc.z * invd, acc.w * invd);
        *(uint2*)&ah1b[(size_t)n * 32 + q * 2] = pk;
    }
}

__device__ __forceinline__ void mac64(const float (*hT)[68], const float (*wt)[64],
                                      int rr, int cr, float acc[4][4]) {
#pragma unroll 8
    for (int k = 0; k < 64; ++k) {
        float4 a = *(const float4*)&hT[k][rr];
        float4 w = *(const float4*)&wt[k][cr];
        acc[0][0] = fmaf(a.x, w.x, acc[0][0]); acc[0][1] = fmaf(a.x, w.y, acc[0][1]);
        acc[0][2] = fmaf(a.x, w.z, acc[0][2]); acc[0][3] = fmaf(a.x, w.w, acc[0][3]);
        acc[1][0] = fmaf(a.y, w.x, acc[1][0]); acc[1][1] = fmaf(a.y, w.y, acc[1][1]);
        acc[1][2] = fmaf(a.y, w.z, acc[1][2]); acc[1][3] = fmaf(a.y, w.w, acc[1][3]);
        acc[2][0] = fmaf(a.z, w.x, acc[2][0]); acc[2][1] = fmaf(a.z, w.y, acc[2][1]);
        acc[2][2] = fmaf(a.z, w.z, acc[2][2]); acc[2][3] = fmaf(a.z, w.w, acc[2][3]);
        acc[3][0] = fmaf(a.w, w.x, acc[3][0]); acc[3][1] = fmaf(a.w, w.y, acc[3][1]);
        acc[3][2] = fmaf(a.w, w.z, acc[3][2]); acc[3][3] = fmaf(a.w, w.w, acc[3][3]);
    }
}

// ---------------------------------------------------------------------------
// Fused node MLP: h2 = relu(h1@W2s + aggh1@W2n + b2); hn = relu(h2@Wnp+bnp);
// ST(bf16) = hn @ Wbig (Wbig mapping computed inline from We1/Wl1).
// ---------------------------------------------------------------------------
__global__ __launch_bounds__(256, 4)
void node_mlp_k(const unsigned* __restrict__ h1b, const unsigned* __restrict__ ah1b,
                const float* __restrict__ W2s, const float* __restrict__ W2n,
                const float* __restrict__ b2, const float* __restrict__ Wnp,
                const float* __restrict__ bnp, const float* __restrict__ We1,
                const float* __restrict__ Wl1, unsigned short* __restrict__ ST, int N) {
    __shared__ __align__(16) float hT[64][68];
    __shared__ __align__(16) float wt[64][64];
    const int t = threadIdx.x;
    const int m0 = blockIdx.x * 64;
    const int cr = (t & 15) << 2, rr = (t >> 4) << 2;
    float acc[4][4] = {};

    // phase A1: self term from bf16 h1
#pragma unroll
    for (int it = 0; it < 8; ++it) {
        int u = it * 256 + t;
        int m = u >> 5, p = u & 31;
        int row = m0 + m;
        unsigned v = (row < N) ? h1b[(size_t)row * 32 + p] : 0u;
        hT[2 * p][m] = bflo(v);
        hT[2 * p + 1][m] = bfhi(v);
    }
#pragma unroll
    for (int it = 0; it < 16; ++it) {
        int k = it * 4 + (t >> 6), c = t & 63;
        wt[k][c] = W2s[k * 64 + c];
    }
    __syncthreads();
    mac64(hT, wt, rr, cr, acc);
    __syncthreads();

    // phase A2: neighbor term from bf16 aggh1
#pragma unroll
    for (int it = 0; it < 8; ++it) {
        int u = it * 256 + t;
        int m = u >> 5, p = u & 31;
        int row = m0 + m;
        unsigned v = (row < N) ? ah1b[(size_t)row * 32 + p] : 0u;
        hT[2 * p][m] = bflo(v);
        hT[2 * p + 1][m] = bfhi(v);
    }
#pragma unroll
    for (int it = 0; it < 16; ++it) {
        int k = it * 4 + (t >> 6), c = t & 63;
        wt[k][c] = W2n[k * 64 + c];
    }
    __syncthreads();
    mac64(hT, wt, rr, cr, acc);
    __syncthreads();

    // h2 -> hT (transposed), wt <- Wnp
#pragma unroll
    for (int i = 0; i < 4; ++i)
#pragma unroll
        for (int q = 0; q < 4; ++q)
            hT[cr + q][rr + i] = fmaxf(acc[i][q] + b2[cr + q], 0.f);
#pragma unroll
    for (int it = 0; it < 16; ++it) {
        int k = it * 4 + (t >> 6), c = t & 63;
        wt[k][c] = Wnp[k * 64 + c];
    }
    __syncthreads();
    float ac2[4][4] = {};
    mac64(hT, wt, rr, cr, ac2);
    __syncthreads();

    // hn -> hT (transposed)
#pragma unroll
    for (int i = 0; i < 4; ++i)
#pragma unroll
        for (int q = 0; q < 4; ++q)
            hT[cr + q][rr + i] = fmaxf(ac2[i][q] + bnp[cr + q], 0.f);
    __syncthreads();

    // 4 column phases of ST = hn @ Wbig (mapping inline)
    for (int cb = 0; cb < 4; ++cb) {
        if (cb) __syncthreads();
#pragma unroll
        for (int it = 0; it < 16; ++it) {
            int k = it * 4 + (t >> 6), c = t & 63;
            int cglob = cb * 64 + c;
            int half = cglob >> 7, cc = cglob & 127;
            int jj = cc >> 1, p = cc & 1;
            const float* W = p ? Wl1 : We1;
            wt[k][c] = W[(half * 64 + k) * 64 + jj];
        }
        __syncthreads();
        float ac3[4][4] = {};
        mac64(hT, wt, rr, cr, ac3);
#pragma unroll
        for (int i = 0; i < 4; ++i) {
            int row = m0 + rr + i;
            if (row >= N) continue;
            ushort4 pk;
            pk.x = f2bf(ac3[i][0]); pk.y = f2bf(ac3[i][1]);
            pk.z = f2bf(ac3[i][2]); pk.w = f2bf(ac3[i][3]);
            *(ushort4*)&ST[(size_t)row * 256 + cb * 64 + cr] = pk;
        }
    }
}

// ---------------------------------------------------------------------------
// Edge scorer: one wave per node (2 nodes/block), 4 edges/wave x 16 lanes.
// ST32[n*128 + c]: c<64 src pair (lo=We1,hi=Wl1) for j=c; c>=64 dst pair.
// Quarter g handles edge slot i+g; lane q covers j0=4q..4q+3 (uint4 load).
// ef read as per-quarter same-address vector loads (HW broadcast, no VALU).
// Reductions are 4-op DPP trees (no DS).
// ---------------------------------------------------------------------------
__global__ __launch_bounds__(128, 8)
void edge_k(const int* __restrict__ off, const int2* __restrict__ csr,
            const float* __restrict__ ef, const unsigned* __restrict__ ST32,
            const float* __restrict__ We1, const float* __restrict__ be1,
            const float* __restrict__ We2, const float* __restrict__ be2,
            const float* __restrict__ Wl1, const float* __restrict__ bl1,
            const float* __restrict__ Wl2, const float* __restrict__ bl2,
            float* __restrict__ out, int N) {
    int n = blockIdx.x * 2 + (threadIdx.x >> 6);
    if (n >= N) return;
    const int l = threadIdx.x & 63;
    const int g = l >> 4;            // edge slot within the 4-edge group
    const int q = l & 15;            // j-group
    const int j0 = q << 2;
    int s0 = off[n], s1 = off[n + 1];
    if (s0 >= s1) return;

    float4 wet[5], wlt[5];
#pragma unroll
    for (int k = 0; k < 5; ++k) {
        wet[k] = *(const float4*)&We1[(128 + k) * 64 + j0];
        wlt[k] = *(const float4*)&Wl1[(128 + k) * 64 + j0];
    }
    const float4 vbe1 = *(const float4*)&be1[j0];
    const float4 vwe2 = *(const float4*)&We2[j0];
    const float4 vbl1 = *(const float4*)&bl1[j0];
    const float4 vwl2 = *(const float4*)&Wl2[j0];
    const float vbe2 = be2[0], vbl2 = bl2[0];

    // dst part (per-node, loaded once): 4 packed pairs
    uint4 pw = *(const uint4*)&ST32[(size_t)n * 128 + 64 + j0];
    const float4 tb = {bflo(pw.x) + vbe1.x, bflo(pw.y) + vbe1.y,
                       bflo(pw.z) + vbe1.z, bflo(pw.w) + vbe1.w};
    const float4 ub = {bfhi(pw.x), bfhi(pw.y), bfhi(pw.z), bfhi(pw.w)};

    for (int i = s0; i < s1; i += 4) {
        int ii = i + g;
        bool act = ii < s1;
        int2 se = csr[act ? ii : s0];                 // quarter-uniform
        uint4 sw = *(const uint4*)&ST32[(size_t)se.x * 128 + j0];
        // per-quarter broadcast ef loads (same address within quarter)
        const float* ep = ef + (size_t)se.y * 5;
        float ek0 = ep[0], ek1 = ep[1], ek2 = ep[2], ek3 = ep[3], ek4 = ep[4];
        float4 t4 = {bflo(sw.x) + tb.x, bflo(sw.y) + tb.y,
                     bflo(sw.z) + tb.z, bflo(sw.w) + tb.w};
        float4 u4 = {bfhi(sw.x) + ub.x, bfhi(sw.y) + ub.y,
                     bfhi(sw.z) + ub.z, bfhi(sw.w) + ub.w};
        float ekk[5] = {ek0, ek1, ek2, ek3, ek4};
#pragma unroll
        for (int k = 0; k < 5; ++k) {
            float ek = ekk[k];
            t4.x = fmaf(ek, wet[k].x, t4.x); t4.y = fmaf(ek, wet[k].y, t4.y);
            t4.z = fmaf(ek, wet[k].z, t4.z); t4.w = fmaf(ek, wet[k].w, t4.w);
            u4.x = fmaf(ek, wlt[k].x, u4.x); u4.y = fmaf(ek, wlt[k].y, u4.y);
            u4.z = fmaf(ek, wlt[k].z, u4.z); u4.w = fmaf(ek, wlt[k].w, u4.w);
        }
        float z = fast_tanh(t4.x) * vwe2.x + fast_tanh(t4.y) * vwe2.y
                + fast_tanh(t4.z) * vwe2.z + fast_tanh(t4.w) * vwe2.w;
        z = dpp_sum16(z);
        float w = fast_sigmoid(z + vbe2);
        float o = fmaxf(fmaf(w, u4.x, vbl1.x), 0.f) * vwl2.x
                + fmaxf(fmaf(w, u4.y, vbl1.y), 0.f) * vwl2.y
                + fmaxf(fmaf(w, u4.z, vbl1.z), 0.f) * vwl2.z
                + fmaxf(fmaf(w, u4.w, vbl1.w), 0.f) * vwl2.w;
        o = dpp_sum16(o);
        if (q == 0 && act) out[se.y] = o + vbl2;      // lanes 0,16,32,48
    }
}

extern "C" void kernel_launch(void* const* d_in, const int* in_sizes, int n_in,
                              void* d_out, int out_size, void* d_ws, size_t ws_size,
                              hipStream_t stream) {
    const float* nf  = (const float*)d_in[0];
    const float* ef  = (const float*)d_in[1];
    const int*   src = (const int*)d_in[2];
    const int*   dst = (const int*)d_in[3];
    const float* W1s = (const float*)d_in[4];
    const float* W1n = (const float*)d_in[5];
    const float* b1  = (const float*)d_in[6];
    const float* W2s = (const float*)d_in[7];
    const float* W2n = (const float*)d_in[8];
    const float* b2  = (const float*)d_in[9];
    const float* Wnp = (const float*)d_in[10];
    const float* bnp = (const float*)d_in[11];
    const float* We1 = (const float*)d_in[12];
    const float* be1 = (const float*)d_in[13];
    const float* We2 = (const float*)d_in[14];
    const float* be2 = (const float*)d_in[15];
    const float* Wl1 = (const float*)d_in[16];
    const float* bl1 = (const float*)d_in[17];
    const float* Wl2 = (const float*)d_in[18];
    const float* bl2 = (const float*)d_in[19];

    const int N = in_sizes[0] / 4;
    const int E = in_sizes[2];

    // ws layout (float units), peak ~274N = ~110 MB (proven budget ~128 MB):
    //  ST(bf16): [0, 128N)      written by node_mlp, read by edge_k
    //  ah1b:     [128N, 160N)   packed bf16 aggh1 (uint[32N])
    //  h1b:      [192N, 224N)   packed bf16 h1 (uint[32N])
    //  csr:      [224N, 256N)   int2[E]
    //  rank:     [256N, 272N)   int[E]
    //  deg:      [272N, 273N)   int[N]
    //  off:      [273N, 274N)+1 int[N+1]
    //  bsum:     off+N+1        int[512]
    float* wsf = (float*)d_ws;
    unsigned short* ST = (unsigned short*)wsf;
    unsigned* ah1b = (unsigned*)(wsf + (size_t)128 * N);
    unsigned* h1b  = (unsigned*)(wsf + (size_t)192 * N);
    int2* csr  = (int2*)(wsf + (size_t)224 * N);
    int*  rank = (int*)(wsf + (size_t)256 * N);
    int*  deg  = (int*)(wsf + (size_t)272 * N);
    int*  off  = deg + N;
    int*  bsum = off + N + 1;
    float* out = (float*)d_out;

    const int nblkN1 = (N + 255) / 256;
    const int nblkE  = (E + 255) / 256;
    const int nblkNw4 = (N + 3) / 4;     // 256-thread, 4 nodes
    const int nblkNw2 = (N + 1) / 2;     // 128-thread, 2 nodes
    const int gemmx  = (N + 63) / 64;

    // CSR build: single atomic pass + scan + atomic-free fill
    hipMemsetAsync(deg, 0, (size_t)N * sizeof(int), stream);
    rank_k<<<nblkE, 256, 0, stream>>>(dst, deg, rank, E);
    scan1_k<<<nblkN1, 256, 0, stream>>>(deg, off, bsum, N);
    scan2_k<<<1, 512, 0, stream>>>(bsum, nblkN1);
    scan3_k<<<nblkN1, 256, 0, stream>>>(off, bsum, N, E);
    fill2_k<<<nblkE, 256, 0, stream>>>(src, dst, off, rank, csr, E);

    // layer 1 (fused aggregate + h1, bf16 out)
    aggh1f_k<<<nblkNw4, 256, 0, stream>>>(off, csr, nf, W1s, W1n, b1,
                                          (unsigned short*)h1b, N);

    // layer 2 gather (bf16 out)
    gatherh1_k<<<nblkNw2, 128, 0, stream>>>(off, csr, h1b, ah1b, N);

    // fused node MLP -> bf16 ST table
    node_mlp_k<<<gemmx, 256, 0, stream>>>(h1b, ah1b, W2s, W2n, b2,
                                          Wnp, bnp, We1, Wl1, ST, N);

    // per-edge scoring
    edge_k<<<nblkNw2, 128, 0, stream>>>(off, csr, ef, (const unsigned*)ST,
                                        We1, be1, We2, be2, Wl1, bl1, Wl2, bl2,
                                        out, N);
}

// Round 10
// 600.724 us; speedup vs baseline: 1.4609x; 1.4609x over previous
//
#include <hip/hip_runtime.h>
#include <math.h>

// ---------------------------------------------------------------------------
// EdgeClassifier: 2x SAGEConv(mean) -> per-node MLP -> edge scorer
//  * layer-1 agg: mean commutes with projection -> aggregate raw nf (4-dim),
//    fused with h1 compute (aggh1f_k), h1 stored packed bf16
//  * CSR: 1 atomic pass (rank) + scan + atomic-free scatter fill
//  * gatherh1: 16 gather rows in flight; aggh1 stored packed bf16
//  * node_mlp_k: h1/aggh1(bf16) -> h2 -> hn -> bf16 ST in LDS
//  * edge_k: 4 edges/wave x 16 lanes x 4 j; broadcast ef loads; NO local
//    arrays in the hot loop (r9 spilled ekk[] to scratch: WRITE 52->576MB);
//    launch_bounds(128,6) = 85-VGPR cap, fits ~70-reg live set spill-free
// ---------------------------------------------------------------------------

__device__ __forceinline__ float fast_tanh(float x) {
    x = fminf(fmaxf(x, -15.f), 15.f);
    float e2 = __expf(2.f * x);
    return (e2 - 1.f) * __builtin_amdgcn_rcpf(e2 + 1.f);
}
__device__ __forceinline__ float fast_sigmoid(float x) {
    x = fminf(fmaxf(x, -60.f), 60.f);
    return __builtin_amdgcn_rcpf(1.f + __expf(-x));
}
__device__ __forceinline__ unsigned short f2bf(float f) {   // RNE
    unsigned u = __float_as_uint(f);
    u = u + 0x7FFFu + ((u >> 16) & 1u);
    return (unsigned short)(u >> 16);
}
__device__ __forceinline__ unsigned pack2bf(float lo, float hi) {
    return ((unsigned)f2bf(hi) << 16) | (unsigned)f2bf(lo);
}
__device__ __forceinline__ float bflo(unsigned u) { return __uint_as_float(u << 16); }
__device__ __forceinline__ float bfhi(unsigned u) { return __uint_as_float(u & 0xFFFF0000u); }

// 16-lane all-reduce sum, pure DPP (no LDS/DS)
__device__ __forceinline__ float dpp_sum16(float x) {
    int t;
    t = __builtin_amdgcn_update_dpp(0, __float_as_int(x), 0xB1, 0xF, 0xF, true);  // quad_perm(1,0,3,2)
    x += __int_as_float(t);
    t = __builtin_amdgcn_update_dpp(0, __float_as_int(x), 0x4E, 0xF, 0xF, true);  // quad_perm(2,3,0,1)
    x += __int_as_float(t);
    t = __builtin_amdgcn_update_dpp(0, __float_as_int(x), 0x141, 0xF, 0xF, true); // row_half_mirror
    x += __int_as_float(t);
    t = __builtin_amdgcn_update_dpp(0, __float_as_int(x), 0x140, 0xF, 0xF, true); // row_mirror
    x += __int_as_float(t);
    return x;
}

// rank[e] = arrival index among edges sharing dst; deg accumulates counts
__global__ void rank_k(const int* __restrict__ dst, int* __restrict__ deg,
                       int* __restrict__ rank, int E) {
    int e = blockIdx.x * blockDim.x + threadIdx.x;
    if (e < E) rank[e] = atomicAdd(&deg[dst[e]], 1);
}

__global__ void scan1_k(const int* __restrict__ deg, int* __restrict__ off,
                        int* __restrict__ bsum, int N) {
    __shared__ int tmp[256];
    int i = blockIdx.x * 256 + threadIdx.x;
    int v = (i < N) ? deg[i] : 0;
    tmp[threadIdx.x] = v;
    __syncthreads();
#pragma unroll
    for (int s = 1; s < 256; s <<= 1) {
        int t = (threadIdx.x >= s) ? tmp[threadIdx.x - s] : 0;
        __syncthreads();
        tmp[threadIdx.x] += t;
        __syncthreads();
    }
    if (i < N) off[i] = tmp[threadIdx.x] - v;
    if (threadIdx.x == 255) bsum[blockIdx.x] = tmp[255];
}

__global__ void scan2_k(int* __restrict__ bsum, int nb) {
    __shared__ int tmp[512];
    int i = threadIdx.x;
    int v = (i < nb) ? bsum[i] : 0;
    tmp[i] = v;
    __syncthreads();
#pragma unroll
    for (int s = 1; s < 512; s <<= 1) {
        int t = (i >= s) ? tmp[i - s] : 0;
        __syncthreads();
        tmp[i] += t;
        __syncthreads();
    }
    if (i < nb) bsum[i] = tmp[i] - v;
}

__global__ void scan3_k(int* __restrict__ off, const int* __restrict__ bsum,
                        int N, int E) {
    int i = blockIdx.x * 256 + threadIdx.x;
    if (i < N) off[i] += bsum[blockIdx.x];
    if (i == 0) off[N] = E;
}

// atomic-free CSR fill using precomputed ranks
__global__ void fill2_k(const int* __restrict__ src, const int* __restrict__ dst,
                        const int* __restrict__ off, const int* __restrict__ rank,
                        int2* __restrict__ csr, int E) {
    int e = blockIdx.x * blockDim.x + threadIdx.x;
    if (e >= E) return;
    csr[off[dst[e]] + rank[e]] = make_int2(src[e], e);
}

// one wave per node: aggnf = mean of nf[neighbors] (butterfly), then
// h1[j] = relu(nf@W1s + aggnf@W1n + b1)[j] per lane, stored as bf16
__global__ __launch_bounds__(256, 8)
void aggh1f_k(const int* __restrict__ off, const int2* __restrict__ csr,
              const float* __restrict__ nf,
              const float* __restrict__ W1s, const float* __restrict__ W1n,
              const float* __restrict__ b1, unsigned short* __restrict__ h1s, int N) {
    int n = blockIdx.x * 4 + (threadIdx.x >> 6);
    if (n >= N) return;
    int l = threadIdx.x & 63;
    int s0 = off[n], s1 = off[n + 1];
    float4 a = {0.f, 0.f, 0.f, 0.f};
    for (int i = s0 + l; i < s1; i += 64) {
        float4 r = ((const float4*)nf)[csr[i].x];
        a.x += r.x; a.y += r.y; a.z += r.z; a.w += r.w;
    }
#pragma unroll
    for (int m = 1; m < 64; m <<= 1) {
        a.x += __shfl_xor(a.x, m);
        a.y += __shfl_xor(a.y, m);
        a.z += __shfl_xor(a.z, m);
        a.w += __shfl_xor(a.w, m);
    }
    float invd = 1.f / fmaxf((float)(s1 - s0), 1.f);
    a.x *= invd; a.y *= invd; a.z *= invd; a.w *= invd;
    float4 r = ((const float4*)nf)[n];
    float v = b1[l]
            + r.x * W1s[l] + r.y * W1s[64 + l] + r.z * W1s[128 + l] + r.w * W1s[192 + l]
            + a.x * W1n[l] + a.y * W1n[64 + l] + a.z * W1n[128 + l] + a.w * W1n[192 + l];
    h1s[(size_t)n * 64 + l] = f2bf(fmaxf(v, 0.f));
}

// one wave per node (2 nodes/block): aggh1b[n] = mean of bf16 h1 rows,
// stored packed bf16. 16 gather rows in flight.
__global__ __launch_bounds__(128, 8)
void gatherh1_k(const int* __restrict__ off, const int2* __restrict__ csr,
                const unsigned* __restrict__ h1b, unsigned* __restrict__ ah1b, int N) {
    int n = blockIdx.x * 2 + (threadIdx.x >> 6);
    if (n >= N) return;
    int l = threadIdx.x & 63;
    int g = l >> 4, q = l & 15;
    int s0 = off[n], s1 = off[n + 1];
    float4 acc = {0.f, 0.f, 0.f, 0.f};
    int i = s0;
    for (; i + 16 <= s1; i += 16) {
        int r0 = csr[i + g].x;
        int r1 = csr[i + 4 + g].x;
        int r2 = csr[i + 8 + g].x;
        int r3 = csr[i + 12 + g].x;
        uint2 v0 = *(const uint2*)&h1b[(size_t)r0 * 32 + q * 2];
        uint2 v1 = *(const uint2*)&h1b[(size_t)r1 * 32 + q * 2];
        uint2 v2 = *(const uint2*)&h1b[(size_t)r2 * 32 + q * 2];
        uint2 v3 = *(const uint2*)&h1b[(size_t)r3 * 32 + q * 2];
        acc.x += (bflo(v0.x) + bflo(v1.x)) + (bflo(v2.x) + bflo(v3.x));
        acc.y += (bfhi(v0.x) + bfhi(v1.x)) + (bfhi(v2.x) + bfhi(v3.x));
        acc.z += (bflo(v0.y) + bflo(v1.y)) + (bflo(v2.y) + bflo(v3.y));
        acc.w += (bfhi(v0.y) + bfhi(v1.y)) + (bfhi(v2.y) + bfhi(v3.y));
    }
    for (; i + 4 <= s1; i += 4) {
        int r0 = csr[i + g].x;
        uint2 v0 = *(const uint2*)&h1b[(size_t)r0 * 32 + q * 2];
        acc.x += bflo(v0.x); acc.y += bfhi(v0.x);
        acc.z += bflo(v0.y); acc.w += bfhi(v0.y);
    }
    int rem = s1 - i;
    if (g < rem) {
        int r0 = csr[i + g].x;
        uint2 v0 = *(const uint2*)&h1b[(size_t)r0 * 32 + q * 2];
        acc.x += bflo(v0.x); acc.y += bfhi(v0.x);
        acc.z += bflo(v0.y); acc.w += bfhi(v0.y);
    }
#pragma unroll
    for (int m = 16; m <= 32; m <<= 1) {
        acc.x += __shfl_xor(acc.x, m);
        acc.y += __shfl_xor(acc.y, m);
        acc.z += __shfl_xor(acc.z, m);
        acc.w += __shfl_xor(acc.w, m);
    }
    if (l < 16) {
        float invd = 1.f / fmaxf((float)(s1 - s0), 1.f);
        uint2 pk;
        pk.x = pack2bf(acc.x * invd, acc.y * invd);
        pk.y = pack2bf(acc.z * invd, acc.w * invd);
        *(uint2*)&ah1b[(size_t)n * 32 + q * 2] = pk;
    }
}

__device__ __forceinline__ void mac64(const float (*hT)[68], const float (*wt)[64],
                                      int rr, int cr, float acc[4][4]) {
#pragma unroll 8
    for (int k = 0; k < 64; ++k) {
        float4 a = *(const float4*)&hT[k][rr];
        float4 w = *(const float4*)&wt[k][cr];
        acc[0][0] = fmaf(a.x, w.x, acc[0][0]); acc[0][1] = fmaf(a.x, w.y, acc[0][1]);
        acc[0][2] = fmaf(a.x, w.z, acc[0][2]); acc[0][3] = fmaf(a.x, w.w, acc[0][3]);
        acc[1][0] = fmaf(a.y, w.x, acc[1][0]); acc[1][1] = fmaf(a.y, w.y, acc[1][1]);
        acc[1][2] = fmaf(a.y, w.z, acc[1][2]); acc[1][3] = fmaf(a.y, w.w, acc[1][3]);
        acc[2][0] = fmaf(a.z, w.x, acc[2][0]); acc[2][1] = fmaf(a.z, w.y, acc[2][1]);
        acc[2][2] = fmaf(a.z, w.z, acc[2][2]); acc[2][3] = fmaf(a.z, w.w, acc[2][3]);
        acc[3][0] = fmaf(a.w, w.x, acc[3][0]); acc[3][1] = fmaf(a.w, w.y, acc[3][1]);
        acc[3][2] = fmaf(a.w, w.z, acc[3][2]); acc[3][3] = fmaf(a.w, w.w, acc[3][3]);
    }
}

// ---------------------------------------------------------------------------
// Fused node MLP: h2 = relu(h1@W2s + aggh1@W2n + b2); hn = relu(h2@Wnp+bnp);
// ST(bf16) = hn @ Wbig (Wbig mapping computed inline from We1/Wl1).
// ---------------------------------------------------------------------------
__global__ __launch_bounds__(256, 4)
void node_mlp_k(const unsigned* __restrict__ h1b, const unsigned* __restrict__ ah1b,
                const float* __restrict__ W2s, const float* __restrict__ W2n,
                const float* __restrict__ b2, const float* __restrict__ Wnp,
                const float* __restrict__ bnp, const float* __restrict__ We1,
                const float* __restrict__ Wl1, unsigned short* __restrict__ ST, int N) {
    __shared__ __align__(16) float hT[64][68];
    __shared__ __align__(16) float wt[64][64];
    const int t = threadIdx.x;
    const int m0 = blockIdx.x * 64;
    const int cr = (t & 15) << 2, rr = (t >> 4) << 2;
    float acc[4][4] = {};

    // phase A1: self term from bf16 h1
#pragma unroll
    for (int it = 0; it < 8; ++it) {
        int u = it * 256 + t;
        int m = u >> 5, p = u & 31;
        int row = m0 + m;
        unsigned v = (row < N) ? h1b[(size_t)row * 32 + p] : 0u;
        hT[2 * p][m] = bflo(v);
        hT[2 * p + 1][m] = bfhi(v);
    }
#pragma unroll
    for (int it = 0; it < 16; ++it) {
        int k = it * 4 + (t >> 6), c = t & 63;
        wt[k][c] = W2s[k * 64 + c];
    }
    __syncthreads();
    mac64(hT, wt, rr, cr, acc);
    __syncthreads();

    // phase A2: neighbor term from bf16 aggh1
#pragma unroll
    for (int it = 0; it < 8; ++it) {
        int u = it * 256 + t;
        int m = u >> 5, p = u & 31;
        int row = m0 + m;
        unsigned v = (row < N) ? ah1b[(size_t)row * 32 + p] : 0u;
        hT[2 * p][m] = bflo(v);
        hT[2 * p + 1][m] = bfhi(v);
    }
#pragma unroll
    for (int it = 0; it < 16; ++it) {
        int k = it * 4 + (t >> 6), c = t & 63;
        wt[k][c] = W2n[k * 64 + c];
    }
    __syncthreads();
    mac64(hT, wt, rr, cr, acc);
    __syncthreads();

    // h2 -> hT (transposed), wt <- Wnp
#pragma unroll
    for (int i = 0; i < 4; ++i)
#pragma unroll
        for (int q = 0; q < 4; ++q)
            hT[cr + q][rr + i] = fmaxf(acc[i][q] + b2[cr + q], 0.f);
#pragma unroll
    for (int it = 0; it < 16; ++it) {
        int k = it * 4 + (t >> 6), c = t & 63;
        wt[k][c] = Wnp[k * 64 + c];
    }
    __syncthreads();
    float ac2[4][4] = {};
    mac64(hT, wt, rr, cr, ac2);
    __syncthreads();

    // hn -> hT (transposed)
#pragma unroll
    for (int i = 0; i < 4; ++i)
#pragma unroll
        for (int q = 0; q < 4; ++q)
            hT[cr + q][rr + i] = fmaxf(ac2[i][q] + bnp[cr + q], 0.f);
    __syncthreads();

    // 4 column phases of ST = hn @ Wbig (mapping inline)
    for (int cb = 0; cb < 4; ++cb) {
        if (cb) __syncthreads();
#pragma unroll
        for (int it = 0; it < 16; ++it) {
            int k = it * 4 + (t >> 6), c = t & 63;
            int cglob = cb * 64 + c;
            int half = cglob >> 7, cc = cglob & 127;
            int jj = cc >> 1, p = cc & 1;
            const float* W = p ? Wl1 : We1;
            wt[k][c] = W[(half * 64 + k) * 64 + jj];
        }
        __syncthreads();
        float ac3[4][4] = {};
        mac64(hT, wt, rr, cr, ac3);
#pragma unroll
        for (int i = 0; i < 4; ++i) {
            int row = m0 + rr + i;
            if (row >= N) continue;
            ushort4 pk;
            pk.x = f2bf(ac3[i][0]); pk.y = f2bf(ac3[i][1]);
            pk.z = f2bf(ac3[i][2]); pk.w = f2bf(ac3[i][3]);
            *(ushort4*)&ST[(size_t)row * 256 + cb * 64 + cr] = pk;
        }
    }
}

// ---------------------------------------------------------------------------
// Edge scorer: one wave per node (2 nodes/block), 4 edges/wave x 16 lanes.
// ST32[n*128 + c]: c<64 src pair (lo=We1,hi=Wl1) for j=c; c>=64 dst pair.
// Quarter g handles edge slot i+g; lane q covers j0=4q..4q+3 (uint4 load).
// ef read as per-quarter same-address loads (HW broadcast). NO local arrays
// in the loop body (round-9 scratch-spill lesson); manual 5-step unroll.
// launch_bounds(128,6) -> 85-VGPR cap, fits live set without spilling.
// ---------------------------------------------------------------------------
__global__ __launch_bounds__(128, 6)
void edge_k(const int* __restrict__ off, const int2* __restrict__ csr,
            const float* __restrict__ ef, const unsigned* __restrict__ ST32,
            const float* __restrict__ We1, const float* __restrict__ be1,
            const float* __restrict__ We2, const float* __restrict__ be2,
            const float* __restrict__ Wl1, const float* __restrict__ bl1,
            const float* __restrict__ Wl2, const float* __restrict__ bl2,
            float* __restrict__ out, int N) {
    int n = blockIdx.x * 2 + (threadIdx.x >> 6);
    if (n >= N) return;
    const int l = threadIdx.x & 63;
    const int g = l >> 4;            // edge slot within the 4-edge group
    const int q = l & 15;            // j-group
    const int j0 = q << 2;
    int s0 = off[n], s1 = off[n + 1];
    if (s0 >= s1) return;

    const float4 we0 = *(const float4*)&We1[128 * 64 + j0];
    const float4 we1 = *(const float4*)&We1[129 * 64 + j0];
    const float4 we2 = *(const float4*)&We1[130 * 64 + j0];
    const float4 we3 = *(const float4*)&We1[131 * 64 + j0];
    const float4 we4 = *(const float4*)&We1[132 * 64 + j0];
    const float4 wl0 = *(const float4*)&Wl1[128 * 64 + j0];
    const float4 wl1 = *(const float4*)&Wl1[129 * 64 + j0];
    const float4 wl2 = *(const float4*)&Wl1[130 * 64 + j0];
    const float4 wl3 = *(const float4*)&Wl1[131 * 64 + j0];
    const float4 wl4 = *(const float4*)&Wl1[132 * 64 + j0];
    const float4 vbe1 = *(const float4*)&be1[j0];
    const float4 vwe2 = *(const float4*)&We2[j0];
    const float4 vbl1 = *(const float4*)&bl1[j0];
    const float4 vwl2 = *(const float4*)&Wl2[j0];
    const float vbe2 = be2[0], vbl2 = bl2[0];

    // dst part (per-node, loaded once): 4 packed pairs
    uint4 pw = *(const uint4*)&ST32[(size_t)n * 128 + 64 + j0];
    const float4 tb = {bflo(pw.x) + vbe1.x, bflo(pw.y) + vbe1.y,
                       bflo(pw.z) + vbe1.z, bflo(pw.w) + vbe1.w};
    const float4 ub = {bfhi(pw.x), bfhi(pw.y), bfhi(pw.z), bfhi(pw.w)};

#define KSTEP(EK, WE, WL) \
    t4.x = fmaf(EK, WE.x, t4.x); t4.y = fmaf(EK, WE.y, t4.y); \
    t4.z = fmaf(EK, WE.z, t4.z); t4.w = fmaf(EK, WE.w, t4.w); \
    u4.x = fmaf(EK, WL.x, u4.x); u4.y = fmaf(EK, WL.y, u4.y); \
    u4.z = fmaf(EK, WL.z, u4.z); u4.w = fmaf(EK, WL.w, u4.w);

    for (int i = s0; i < s1; i += 4) {
        int ii = i + g;
        bool act = ii < s1;
        int2 se = csr[act ? ii : s0];                 // quarter-uniform
        uint4 sw = *(const uint4*)&ST32[(size_t)se.x * 128 + j0];
        const float* ep = ef + (size_t)se.y * 5;      // per-quarter broadcast
        float ek0 = ep[0], ek1 = ep[1], ek2 = ep[2], ek3 = ep[3], ek4 = ep[4];
        float4 t4 = {bflo(sw.x) + tb.x, bflo(sw.y) + tb.y,
                     bflo(sw.z) + tb.z, bflo(sw.w) + tb.w};
        float4 u4 = {bfhi(sw.x) + ub.x, bfhi(sw.y) + ub.y,
                     bfhi(sw.z) + ub.z, bfhi(sw.w) + ub.w};
        KSTEP(ek0, we0, wl0)
        KSTEP(ek1, we1, wl1)
        KSTEP(ek2, we2, wl2)
        KSTEP(ek3, we3, wl3)
        KSTEP(ek4, we4, wl4)
        float z = fast_tanh(t4.x) * vwe2.x + fast_tanh(t4.y) * vwe2.y
                + fast_tanh(t4.z) * vwe2.z + fast_tanh(t4.w) * vwe2.w;
        z = dpp_sum16(z);
        float w = fast_sigmoid(z + vbe2);
        float o = fmaxf(fmaf(w, u4.x, vbl1.x), 0.f) * vwl2.x
                + fmaxf(fmaf(w, u4.y, vbl1.y), 0.f) * vwl2.y
                + fmaxf(fmaf(w, u4.z, vbl1.z), 0.f) * vwl2.z
                + fmaxf(fmaf(w, u4.w, vbl1.w), 0.f) * vwl2.w;
        o = dpp_sum16(o);
        if (q == 0 && act) out[se.y] = o + vbl2;      // lanes 0,16,32,48
    }
#undef KSTEP
}

extern "C" void kernel_launch(void* const* d_in, const int* in_sizes, int n_in,
                              void* d_out, int out_size, void* d_ws, size_t ws_size,
                              hipStream_t stream) {
    const float* nf  = (const float*)d_in[0];
    const float* ef  = (const float*)d_in[1];
    const int*   src = (const int*)d_in[2];
    const int*   dst = (const int*)d_in[3];
    const float* W1s = (const float*)d_in[4];
    const float* W1n = (const float*)d_in[5];
    const float* b1  = (const float*)d_in[6];
    const float* W2s = (const float*)d_in[7];
    const float* W2n = (const float*)d_in[8];
    const float* b2  = (const float*)d_in[9];
    const float* Wnp = (const float*)d_in[10];
    const float* bnp = (const float*)d_in[11];
    const float* We1 = (const float*)d_in[12];
    const float* be1 = (const float*)d_in[13];
    const float* We2 = (const float*)d_in[14];
    const float* be2 = (const float*)d_in[15];
    const float* Wl1 = (const float*)d_in[16];
    const float* bl1 = (const float*)d_in[17];
    const float* Wl2 = (const float*)d_in[18];
    const float* bl2 = (const float*)d_in[19];

    const int N = in_sizes[0] / 4;
    const int E = in_sizes[2];

    // ws layout (float units), peak ~274N = ~110 MB (proven budget ~128 MB):
    //  ST(bf16): [0, 128N)      written by node_mlp, read by edge_k
    //  ah1b:     [128N, 160N)   packed bf16 aggh1 (uint[32N])
    //  h1b:      [192N, 224N)   packed bf16 h1 (uint[32N])
    //  csr:      [224N, 256N)   int2[E]
    //  rank:     [256N, 272N)   int[E]
    //  deg:      [272N, 273N)   int[N]
    //  off:      [273N, 274N)+1 int[N+1]
    //  bsum:     off+N+1        int[512]
    float* wsf = (float*)d_ws;
    unsigned short* ST = (unsigned short*)wsf;
    unsigned* ah1b = (unsigned*)(wsf + (size_t)128 * N);
    unsigned* h1b  = (unsigned*)(wsf + (size_t)192 * N);
    int2* csr  = (int2*)(wsf + (size_t)224 * N);
    int*  rank = (int*)(wsf + (size_t)256 * N);
    int*  deg  = (int*)(wsf + (size_t)272 * N);
    int*  off  = deg + N;
    int*  bsum = off + N + 1;
    float* out = (float*)d_out;

    const int nblkN1 = (N + 255) / 256;
    const int nblkE  = (E + 255) / 256;
    const int nblkNw4 = (N + 3) / 4;     // 256-thread, 4 nodes
    const int nblkNw2 = (N + 1) / 2;     // 128-thread, 2 nodes
    const int gemmx  = (N + 63) / 64;

    // CSR build: single atomic pass + scan + atomic-free fill
    hipMemsetAsync(deg, 0, (size_t)N * sizeof(int), stream);
    rank_k<<<nblkE, 256, 0, stream>>>(dst, deg, rank, E);
    scan1_k<<<nblkN1, 256, 0, stream>>>(deg, off, bsum, N);
    scan2_k<<<1, 512, 0, stream>>>(bsum, nblkN1);
    scan3_k<<<nblkN1, 256, 0, stream>>>(off, bsum, N, E);
    fill2_k<<<nblkE, 256, 0, stream>>>(src, dst, off, rank, csr, E);

    // layer 1 (fused aggregate + h1, bf16 out)
    aggh1f_k<<<nblkNw4, 256, 0, stream>>>(off, csr, nf, W1s, W1n, b1,
                                          (unsigned short*)h1b, N);

    // layer 2 gather (bf16 out)
    gatherh1_k<<<nblkNw2, 128, 0, stream>>>(off, csr, h1b, ah1b, N);

    // fused node MLP -> bf16 ST table
    node_mlp_k<<<gemmx, 256, 0, stream>>>(h1b, ah1b, W2s, W2n, b2,
                                          Wnp, bnp, We1, Wl1, ST, N);

    // per-edge scoring
    edge_k<<<nblkNw2, 128, 0, stream>>>(off, csr, ef, (const unsigned*)ST,
                                        We1, be1, We2, be2, Wl1, bl1, Wl2, bl2,
                                        out, N);
}

// Round 11
// 543.916 us; speedup vs baseline: 1.6134x; 1.1044x over previous
//
#include <hip/hip_runtime.h>
#include <math.h>

// ---------------------------------------------------------------------------
// EdgeClassifier: 2x SAGEConv(mean) -> per-node MLP -> edge scorer
//  * layer-1 agg: mean commutes with projection -> aggregate raw nf (4-dim),
//    fused with h1 compute (aggh1f_k), h1 stored packed bf16
//  * CSR: 1 atomic pass (rank) + scan + atomic-free scatter fill
//  * gatherh1: uint4 loads, 8 rows in flight; aggh1 stored packed bf16
//  * node_mlp_k: h1/aggh1(bf16) -> h2 -> hn -> bf16 ST in LDS
//  * edge_k: PROVEN round-8 version (188us): 4 edges/wave x 16 lanes x 4 j,
//    readlane ef + cndmask, DPP reductions, NO launch_bounds (lesson r9/r10:
//    any VGPR cap below the ~95-reg live set forces scratch spill; unbounded,
//    the compiler re-loads weights from L1 instead -- 52MB vs 120-576MB WRITE)
// ---------------------------------------------------------------------------

__device__ __forceinline__ float fast_tanh(float x) {
    x = fminf(fmaxf(x, -15.f), 15.f);
    float e2 = __expf(2.f * x);
    return (e2 - 1.f) * __builtin_amdgcn_rcpf(e2 + 1.f);
}
__device__ __forceinline__ float fast_sigmoid(float x) {
    x = fminf(fmaxf(x, -60.f), 60.f);
    return __builtin_amdgcn_rcpf(1.f + __expf(-x));
}
__device__ __forceinline__ unsigned short f2bf(float f) {   // RNE
    unsigned u = __float_as_uint(f);
    u = u + 0x7FFFu + ((u >> 16) & 1u);
    return (unsigned short)(u >> 16);
}
__device__ __forceinline__ unsigned pack2bf(float lo, float hi) {
    return ((unsigned)f2bf(hi) << 16) | (unsigned)f2bf(lo);
}
__device__ __forceinline__ float bflo(unsigned u) { return __uint_as_float(u << 16); }
__device__ __forceinline__ float bfhi(unsigned u) { return __uint_as_float(u & 0xFFFF0000u); }

// 16-lane all-reduce sum, pure DPP (no LDS/DS)
__device__ __forceinline__ float dpp_sum16(float x) {
    int t;
    t = __builtin_amdgcn_update_dpp(0, __float_as_int(x), 0xB1, 0xF, 0xF, true);  // quad_perm(1,0,3,2)
    x += __int_as_float(t);
    t = __builtin_amdgcn_update_dpp(0, __float_as_int(x), 0x4E, 0xF, 0xF, true);  // quad_perm(2,3,0,1)
    x += __int_as_float(t);
    t = __builtin_amdgcn_update_dpp(0, __float_as_int(x), 0x141, 0xF, 0xF, true); // row_half_mirror
    x += __int_as_float(t);
    t = __builtin_amdgcn_update_dpp(0, __float_as_int(x), 0x140, 0xF, 0xF, true); // row_mirror
    x += __int_as_float(t);
    return x;
}

// rank[e] = arrival index among edges sharing dst; deg accumulates counts
__global__ void rank_k(const int* __restrict__ dst, int* __restrict__ deg,
                       int* __restrict__ rank, int E) {
    int e = blockIdx.x * blockDim.x + threadIdx.x;
    if (e < E) rank[e] = atomicAdd(&deg[dst[e]], 1);
}

__global__ void scan1_k(const int* __restrict__ deg, int* __restrict__ off,
                        int* __restrict__ bsum, int N) {
    __shared__ int tmp[256];
    int i = blockIdx.x * 256 + threadIdx.x;
    int v = (i < N) ? deg[i] : 0;
    tmp[threadIdx.x] = v;
    __syncthreads();
#pragma unroll
    for (int s = 1; s < 256; s <<= 1) {
        int t = (threadIdx.x >= s) ? tmp[threadIdx.x - s] : 0;
        __syncthreads();
        tmp[threadIdx.x] += t;
        __syncthreads();
    }
    if (i < N) off[i] = tmp[threadIdx.x] - v;
    if (threadIdx.x == 255) bsum[blockIdx.x] = tmp[255];
}

__global__ void scan2_k(int* __restrict__ bsum, int nb) {
    __shared__ int tmp[512];
    int i = threadIdx.x;
    int v = (i < nb) ? bsum[i] : 0;
    tmp[i] = v;
    __syncthreads();
#pragma unroll
    for (int s = 1; s < 512; s <<= 1) {
        int t = (i >= s) ? tmp[i - s] : 0;
        __syncthreads();
        tmp[i] += t;
        __syncthreads();
    }
    if (i < nb) bsum[i] = tmp[i] - v;
}

__global__ void scan3_k(int* __restrict__ off, const int* __restrict__ bsum,
                        int N, int E) {
    int i = blockIdx.x * 256 + threadIdx.x;
    if (i < N) off[i] += bsum[blockIdx.x];
    if (i == 0) off[N] = E;
}

// atomic-free CSR fill using precomputed ranks
__global__ void fill2_k(const int* __restrict__ src, const int* __restrict__ dst,
                        const int* __restrict__ off, const int* __restrict__ rank,
                        int2* __restrict__ csr, int E) {
    int e = blockIdx.x * blockDim.x + threadIdx.x;
    if (e >= E) return;
    csr[off[dst[e]] + rank[e]] = make_int2(src[e], e);
}

// one wave per node: aggnf = mean of nf[neighbors] (butterfly), then
// h1[j] = relu(nf@W1s + aggnf@W1n + b1)[j] per lane, stored as bf16
__global__ __launch_bounds__(256, 8)
void aggh1f_k(const int* __restrict__ off, const int2* __restrict__ csr,
              const float* __restrict__ nf,
              const float* __restrict__ W1s, const float* __restrict__ W1n,
              const float* __restrict__ b1, unsigned short* __restrict__ h1s, int N) {
    int n = blockIdx.x * 4 + (threadIdx.x >> 6);
    if (n >= N) return;
    int l = threadIdx.x & 63;
    int s0 = off[n], s1 = off[n + 1];
    float4 a = {0.f, 0.f, 0.f, 0.f};
    for (int i = s0 + l; i < s1; i += 64) {
        float4 r = ((const float4*)nf)[csr[i].x];
        a.x += r.x; a.y += r.y; a.z += r.z; a.w += r.w;
    }
#pragma unroll
    for (int m = 1; m < 64; m <<= 1) {
        a.x += __shfl_xor(a.x, m);
        a.y += __shfl_xor(a.y, m);
        a.z += __shfl_xor(a.z, m);
        a.w += __shfl_xor(a.w, m);
    }
    float invd = 1.f / fmaxf((float)(s1 - s0), 1.f);
    a.x *= invd; a.y *= invd; a.z *= invd; a.w *= invd;
    float4 r = ((const float4*)nf)[n];
    float v = b1[l]
            + r.x * W1s[l] + r.y * W1s[64 + l] + r.z * W1s[128 + l] + r.w * W1s[192 + l]
            + a.x * W1n[l] + a.y * W1n[64 + l] + a.z * W1n[128 + l] + a.w * W1n[192 + l];
    h1s[(size_t)n * 64 + l] = f2bf(fmaxf(v, 0.f));
}

// one wave per node (4 nodes/block): aggh1b[n] = mean of bf16 h1 rows.
// lane l: slot g=l>>3 (8 rows in flight), octet q=l&7 -> features 8q..8q+7
// via one uint4 (16 B) load. Reduce across slots with xor {8,16,32}.
__global__ __launch_bounds__(256, 8)
void gatherh1_k(const int* __restrict__ off, const int2* __restrict__ csr,
                const uint4* __restrict__ h1b4, uint4* __restrict__ ah1b4, int N) {
    int n = blockIdx.x * 4 + (threadIdx.x >> 6);
    if (n >= N) return;
    int l = threadIdx.x & 63;
    int g = l >> 3, q = l & 7;
    int s0 = off[n], s1 = off[n + 1];
    float a0 = 0.f, a1 = 0.f, a2 = 0.f, a3 = 0.f;
    float a4 = 0.f, a5 = 0.f, a6 = 0.f, a7 = 0.f;
    int i = s0;
    for (; i + 8 <= s1; i += 8) {
        int r = csr[i + g].x;
        uint4 v = h1b4[(size_t)r * 8 + q];
        a0 += bflo(v.x); a1 += bfhi(v.x);
        a2 += bflo(v.y); a3 += bfhi(v.y);
        a4 += bflo(v.z); a5 += bfhi(v.z);
        a6 += bflo(v.w); a7 += bfhi(v.w);
    }
    int rem = s1 - i;
    if (g < rem) {
        int r = csr[i + g].x;
        uint4 v = h1b4[(size_t)r * 8 + q];
        a0 += bflo(v.x); a1 += bfhi(v.x);
        a2 += bflo(v.y); a3 += bfhi(v.y);
        a4 += bflo(v.z); a5 += bfhi(v.z);
        a6 += bflo(v.w); a7 += bfhi(v.w);
    }
#pragma unroll
    for (int m = 8; m <= 32; m <<= 1) {
        a0 += __shfl_xor(a0, m); a1 += __shfl_xor(a1, m);
        a2 += __shfl_xor(a2, m); a3 += __shfl_xor(a3, m);
        a4 += __shfl_xor(a4, m); a5 += __shfl_xor(a5, m);
        a6 += __shfl_xor(a6, m); a7 += __shfl_xor(a7, m);
    }
    if (l < 8) {
        float invd = 1.f / fmaxf((float)(s1 - s0), 1.f);
        uint4 pk;
        pk.x = pack2bf(a0 * invd, a1 * invd);
        pk.y = pack2bf(a2 * invd, a3 * invd);
        pk.z = pack2bf(a4 * invd, a5 * invd);
        pk.w = pack2bf(a6 * invd, a7 * invd);
        ah1b4[(size_t)n * 8 + q] = pk;
    }
}

__device__ __forceinline__ void mac64(const float (*hT)[68], const float (*wt)[64],
                                      int rr, int cr, float acc[4][4]) {
#pragma unroll 8
    for (int k = 0; k < 64; ++k) {
        float4 a = *(const float4*)&hT[k][rr];
        float4 w = *(const float4*)&wt[k][cr];
        acc[0][0] = fmaf(a.x, w.x, acc[0][0]); acc[0][1] = fmaf(a.x, w.y, acc[0][1]);
        acc[0][2] = fmaf(a.x, w.z, acc[0][2]); acc[0][3] = fmaf(a.x, w.w, acc[0][3]);
        acc[1][0] = fmaf(a.y, w.x, acc[1][0]); acc[1][1] = fmaf(a.y, w.y, acc[1][1]);
        acc[1][2] = fmaf(a.y, w.z, acc[1][2]); acc[1][3] = fmaf(a.y, w.w, acc[1][3]);
        acc[2][0] = fmaf(a.z, w.x, acc[2][0]); acc[2][1] = fmaf(a.z, w.y, acc[2][1]);
        acc[2][2] = fmaf(a.z, w.z, acc[2][2]); acc[2][3] = fmaf(a.z, w.w, acc[2][3]);
        acc[3][0] = fmaf(a.w, w.x, acc[3][0]); acc[3][1] = fmaf(a.w, w.y, acc[3][1]);
        acc[3][2] = fmaf(a.w, w.z, acc[3][2]); acc[3][3] = fmaf(a.w, w.w, acc[3][3]);
    }
}

// ---------------------------------------------------------------------------
// Fused node MLP: h2 = relu(h1@W2s + aggh1@W2n + b2); hn = relu(h2@Wnp+bnp);
// ST(bf16) = hn @ Wbig (Wbig mapping computed inline from We1/Wl1).
// ---------------------------------------------------------------------------
__global__ __launch_bounds__(256, 4)
void node_mlp_k(const unsigned* __restrict__ h1b, const unsigned* __restrict__ ah1b,
                const float* __restrict__ W2s, const float* __restrict__ W2n,
                const float* __restrict__ b2, const float* __restrict__ Wnp,
                const float* __restrict__ bnp, const float* __restrict__ We1,
                const float* __restrict__ Wl1, unsigned short* __restrict__ ST, int N) {
    __shared__ __align__(16) float hT[64][68];
    __shared__ __align__(16) float wt[64][64];
    const int t = threadIdx.x;
    const int m0 = blockIdx.x * 64;
    const int cr = (t & 15) << 2, rr = (t >> 4) << 2;
    float acc[4][4] = {};

    // phase A1: self term from bf16 h1
#pragma unroll
    for (int it = 0; it < 8; ++it) {
        int u = it * 256 + t;
        int m = u >> 5, p = u & 31;
        int row = m0 + m;
        unsigned v = (row < N) ? h1b[(size_t)row * 32 + p] : 0u;
        hT[2 * p][m] = bflo(v);
        hT[2 * p + 1][m] = bfhi(v);
    }
#pragma unroll
    for (int it = 0; it < 16; ++it) {
        int k = it * 4 + (t >> 6), c = t & 63;
        wt[k][c] = W2s[k * 64 + c];
    }
    __syncthreads();
    mac64(hT, wt, rr, cr, acc);
    __syncthreads();

    // phase A2: neighbor term from bf16 aggh1
#pragma unroll
    for (int it = 0; it < 8; ++it) {
        int u = it * 256 + t;
        int m = u >> 5, p = u & 31;
        int row = m0 + m;
        unsigned v = (row < N) ? ah1b[(size_t)row * 32 + p] : 0u;
        hT[2 * p][m] = bflo(v);
        hT[2 * p + 1][m] = bfhi(v);
    }
#pragma unroll
    for (int it = 0; it < 16; ++it) {
        int k = it * 4 + (t >> 6), c = t & 63;
        wt[k][c] = W2n[k * 64 + c];
    }
    __syncthreads();
    mac64(hT, wt, rr, cr, acc);
    __syncthreads();

    // h2 -> hT (transposed), wt <- Wnp
#pragma unroll
    for (int i = 0; i < 4; ++i)
#pragma unroll
        for (int q = 0; q < 4; ++q)
            hT[cr + q][rr + i] = fmaxf(acc[i][q] + b2[cr + q], 0.f);
#pragma unroll
    for (int it = 0; it < 16; ++it) {
        int k = it * 4 + (t >> 6), c = t & 63;
        wt[k][c] = Wnp[k * 64 + c];
    }
    __syncthreads();
    float ac2[4][4] = {};
    mac64(hT, wt, rr, cr, ac2);
    __syncthreads();

    // hn -> hT (transposed)
#pragma unroll
    for (int i = 0; i < 4; ++i)
#pragma unroll
        for (int q = 0; q < 4; ++q)
            hT[cr + q][rr + i] = fmaxf(ac2[i][q] + bnp[cr + q], 0.f);
    __syncthreads();

    // 4 column phases of ST = hn @ Wbig (mapping inline)
    for (int cb = 0; cb < 4; ++cb) {
        if (cb) __syncthreads();
#pragma unroll
        for (int it = 0; it < 16; ++it) {
            int k = it * 4 + (t >> 6), c = t & 63;
            int cglob = cb * 64 + c;
            int half = cglob >> 7, cc = cglob & 127;
            int jj = cc >> 1, p = cc & 1;
            const float* W = p ? Wl1 : We1;
            wt[k][c] = W[(half * 64 + k) * 64 + jj];
        }
        __syncthreads();
        float ac3[4][4] = {};
        mac64(hT, wt, rr, cr, ac3);
#pragma unroll
        for (int i = 0; i < 4; ++i) {
            int row = m0 + rr + i;
            if (row >= N) continue;
            ushort4 pk;
            pk.x = f2bf(ac3[i][0]); pk.y = f2bf(ac3[i][1]);
            pk.z = f2bf(ac3[i][2]); pk.w = f2bf(ac3[i][3]);
            *(ushort4*)&ST[(size_t)row * 256 + cb * 64 + cr] = pk;
        }
    }
}

// ---------------------------------------------------------------------------
// Edge scorer: PROVEN round-8 version (188 us, VGPR 44, no spill).
// One wave per node (4 nodes/256-thr block), 4 edges/wave x 16 lanes x 4 j.
// ST32[n*128 + c]: c<64 src pair (lo=We1,hi=Wl1) for j=c; c>=64 dst pair.
// Quarter g handles edge slot i+g; lane q covers j0=4q..4q+3 (uint4 load).
// ef rows scalar via readlane + cndmask select; 4-op DPP reductions.
// NO __launch_bounds__ (r9/r10 lesson: caps force scratch spill here).
// ---------------------------------------------------------------------------
__global__ void edge_k(const int* __restrict__ off, const int2* __restrict__ csr,
                       const float* __restrict__ ef, const unsigned* __restrict__ ST32,
                       const float* __restrict__ We1, const float* __restrict__ be1,
                       const float* __restrict__ We2, const float* __restrict__ be2,
                       const float* __restrict__ Wl1, const float* __restrict__ bl1,
                       const float* __restrict__ Wl2, const float* __restrict__ bl2,
                       float* __restrict__ out, int N) {
    int n = blockIdx.x * 4 + (threadIdx.x >> 6);
    if (n >= N) return;
    const int l = threadIdx.x & 63;
    const int g = l >> 4;            // edge slot within the 4-edge group
    const int q = l & 15;            // j-group
    const int j0 = q << 2;
    int s0 = off[n], s1 = off[n + 1];
    if (s0 >= s1) return;

    float4 wet[5], wlt[5];
#pragma unroll
    for (int k = 0; k < 5; ++k) {
        wet[k] = *(const float4*)&We1[(128 + k) * 64 + j0];
        wlt[k] = *(const float4*)&Wl1[(128 + k) * 64 + j0];
    }
    const float4 vbe1 = *(const float4*)&be1[j0];
    const float4 vwe2 = *(const float4*)&We2[j0];
    const float4 vbl1 = *(const float4*)&bl1[j0];
    const float4 vwl2 = *(const float4*)&Wl2[j0];
    const float vbe2 = be2[0], vbl2 = bl2[0];

    // dst part (per-node, loaded once): 4 packed pairs
    uint4 pw = *(const uint4*)&ST32[(size_t)n * 128 + 64 + j0];
    const float4 tb = {bflo(pw.x) + vbe1.x, bflo(pw.y) + vbe1.y,
                       bflo(pw.z) + vbe1.z, bflo(pw.w) + vbe1.w};
    const float4 ub = {bfhi(pw.x), bfhi(pw.y), bfhi(pw.z), bfhi(pw.w)};

    const bool gb1 = (g & 1), gb2 = (g & 2);

    for (int i = s0; i < s1; i += 4) {
        int ii = i + g;
        bool act = ii < s1;
        int2 se = csr[act ? ii : s0];                 // quarter-uniform
        uint4 sw = *(const uint4*)&ST32[(size_t)se.x * 128 + j0];
        float4 t4 = {bflo(sw.x) + tb.x, bflo(sw.y) + tb.y,
                     bflo(sw.z) + tb.z, bflo(sw.w) + tb.w};
        float4 u4 = {bfhi(sw.x) + ub.x, bfhi(sw.y) + ub.y,
                     bfhi(sw.z) + ub.z, bfhi(sw.w) + ub.w};
        // scalar ef rows for the 4 edges
        int e0 = __builtin_amdgcn_readlane(se.y, 0);
        int e1 = __builtin_amdgcn_readlane(se.y, 16);
        int e2 = __builtin_amdgcn_readlane(se.y, 32);
        int e3 = __builtin_amdgcn_readlane(se.y, 48);
        const float* p0 = ef + (size_t)e0 * 5;
        const float* p1 = ef + (size_t)e1 * 5;
        const float* p2 = ef + (size_t)e2 * 5;
        const float* p3 = ef + (size_t)e3 * 5;
#pragma unroll
        for (int k = 0; k < 5; ++k) {
            float a01 = gb1 ? p1[k] : p0[k];
            float a23 = gb1 ? p3[k] : p2[k];
            float ek  = gb2 ? a23 : a01;
            t4.x = fmaf(ek, wet[k].x, t4.x); t4.y = fmaf(ek, wet[k].y, t4.y);
            t4.z = fmaf(ek, wet[k].z, t4.z); t4.w = fmaf(ek, wet[k].w, t4.w);
            u4.x = fmaf(ek, wlt[k].x, u4.x); u4.y = fmaf(ek, wlt[k].y, u4.y);
            u4.z = fmaf(ek, wlt[k].z, u4.z); u4.w = fmaf(ek, wlt[k].w, u4.w);
        }
        float z = fast_tanh(t4.x) * vwe2.x + fast_tanh(t4.y) * vwe2.y
                + fast_tanh(t4.z) * vwe2.z + fast_tanh(t4.w) * vwe2.w;
        z = dpp_sum16(z);
        float w = fast_sigmoid(z + vbe2);
        float o = fmaxf(fmaf(w, u4.x, vbl1.x), 0.f) * vwl2.x
                + fmaxf(fmaf(w, u4.y, vbl1.y), 0.f) * vwl2.y
                + fmaxf(fmaf(w, u4.z, vbl1.z), 0.f) * vwl2.z
                + fmaxf(fmaf(w, u4.w, vbl1.w), 0.f) * vwl2.w;
        o = dpp_sum16(o);
        if (q == 0 && act) out[se.y] = o + vbl2;      // lanes 0,16,32,48
    }
}

extern "C" void kernel_launch(void* const* d_in, const int* in_sizes, int n_in,
                              void* d_out, int out_size, void* d_ws, size_t ws_size,
                              hipStream_t stream) {
    const float* nf  = (const float*)d_in[0];
    const float* ef  = (const float*)d_in[1];
    const int*   src = (const int*)d_in[2];
    const int*   dst = (const int*)d_in[3];
    const float* W1s = (const float*)d_in[4];
    const float* W1n = (const float*)d_in[5];
    const float* b1  = (const float*)d_in[6];
    const float* W2s = (const float*)d_in[7];
    const float* W2n = (const float*)d_in[8];
    const float* b2  = (const float*)d_in[9];
    const float* Wnp = (const float*)d_in[10];
    const float* bnp = (const float*)d_in[11];
    const float* We1 = (const float*)d_in[12];
    const float* be1 = (const float*)d_in[13];
    const float* We2 = (const float*)d_in[14];
    const float* be2 = (const float*)d_in[15];
    const float* Wl1 = (const float*)d_in[16];
    const float* bl1 = (const float*)d_in[17];
    const float* Wl2 = (const float*)d_in[18];
    const float* bl2 = (const float*)d_in[19];

    const int N = in_sizes[0] / 4;
    const int E = in_sizes[2];

    // ws layout (float units), peak ~274N = ~110 MB (proven budget ~128 MB):
    //  ST(bf16): [0, 128N)      written by node_mlp, read by edge_k
    //  ah1b:     [128N, 160N)   packed bf16 aggh1 (uint[32N])
    //  h1b:      [192N, 224N)   packed bf16 h1 (uint[32N])
    //  csr:      [224N, 256N)   int2[E]
    //  rank:     [256N, 272N)   int[E]
    //  deg:      [272N, 273N)   int[N]
    //  off:      [273N, 274N)+1 int[N+1]
    //  bsum:     off+N+1        int[512]
    float* wsf = (float*)d_ws;
    unsigned short* ST = (unsigned short*)wsf;
    unsigned* ah1b = (unsigned*)(wsf + (size_t)128 * N);
    unsigned* h1b  = (unsigned*)(wsf + (size_t)192 * N);
    int2* csr  = (int2*)(wsf + (size_t)224 * N);
    int*  rank = (int*)(wsf + (size_t)256 * N);
    int*  deg  = (int*)(wsf + (size_t)272 * N);
    int*  off  = deg + N;
    int*  bsum = off + N + 1;
    float* out = (float*)d_out;

    const int nblkN1 = (N + 255) / 256;
    const int nblkE  = (E + 255) / 256;
    const int nblkNw4 = (N + 3) / 4;     // 256-thread, 4 nodes
    const int gemmx  = (N + 63) / 64;

    // CSR build: single atomic pass + scan + atomic-free fill
    hipMemsetAsync(deg, 0, (size_t)N * sizeof(int), stream);
    rank_k<<<nblkE, 256, 0, stream>>>(dst, deg, rank, E);
    scan1_k<<<nblkN1, 256, 0, stream>>>(deg, off, bsum, N);
    scan2_k<<<1, 512, 0, stream>>>(bsum, nblkN1);
    scan3_k<<<nblkN1, 256, 0, stream>>>(off, bsum, N, E);
    fill2_k<<<nblkE, 256, 0, stream>>>(src, dst, off, rank, csr, E);

    // layer 1 (fused aggregate + h1, bf16 out)
    aggh1f_k<<<nblkNw4, 256, 0, stream>>>(off, csr, nf, W1s, W1n, b1,
                                          (unsigned short*)h1b, N);

    // layer 2 gather (bf16 out, uint4/8-row)
    gatherh1_k<<<nblkNw4, 256, 0, stream>>>(off, csr, (const uint4*)h1b,
                                            (uint4*)ah1b, N);

    // fused node MLP -> bf16 ST table
    node_mlp_k<<<gemmx, 256, 0, stream>>>(h1b, ah1b, W2s, W2n, b2,
                                          Wnp, bnp, We1, Wl1, ST, N);

    // per-edge scoring
    edge_k<<<nblkNw4, 256, 0, stream>>>(off, csr, ef, (const unsigned*)ST,
                                        We1, be1, We2, be2, Wl1, bl1, Wl2, bl2,
                                        out, N);
}

// Round 12
// 523.929 us; speedup vs baseline: 1.6750x; 1.0381x over previous
//
#include <hip/hip_runtime.h>
#include <math.h>

// ---------------------------------------------------------------------------
// EdgeClassifier: 2x SAGEConv(mean) -> per-node MLP -> edge scorer
//  * layer-1 agg: mean commutes with projection -> aggregate raw nf (4-dim),
//    fused with h1 compute (aggh1f_k), h1 stored packed bf16
//  * CSR: 1 atomic pass (rank) + scan + atomic-free scatter fill
//  * gatherh1: uint4 loads, 16 rows in flight; aggh1 stored packed bf16
//  * node_mlp_k: h1/aggh1(bf16) -> h2 -> hn -> bf16 ST in LDS
//  * edge_k: balanced grid-stride over 4-edge CSR chunks (no per-node tail);
//    dst row via dst[eid] gather (L1/L2-hit for same-node runs); readlane ef
//    + cndmask; DPP reductions; NO launch_bounds (r9/r10: VGPR caps below the
//    ~95-reg live set force scratch spill -- WRITE 52 -> 120-576 MB)
// ---------------------------------------------------------------------------

__device__ __forceinline__ float fast_tanh(float x) {
    x = fminf(fmaxf(x, -15.f), 15.f);
    float e2 = __expf(2.f * x);
    return (e2 - 1.f) * __builtin_amdgcn_rcpf(e2 + 1.f);
}
__device__ __forceinline__ float fast_sigmoid(float x) {
    x = fminf(fmaxf(x, -60.f), 60.f);
    return __builtin_amdgcn_rcpf(1.f + __expf(-x));
}
__device__ __forceinline__ unsigned short f2bf(float f) {   // RNE
    unsigned u = __float_as_uint(f);
    u = u + 0x7FFFu + ((u >> 16) & 1u);
    return (unsigned short)(u >> 16);
}
__device__ __forceinline__ unsigned pack2bf(float lo, float hi) {
    return ((unsigned)f2bf(hi) << 16) | (unsigned)f2bf(lo);
}
__device__ __forceinline__ float bflo(unsigned u) { return __uint_as_float(u << 16); }
__device__ __forceinline__ float bfhi(unsigned u) { return __uint_as_float(u & 0xFFFF0000u); }

// 16-lane all-reduce sum, pure DPP (no LDS/DS)
__device__ __forceinline__ float dpp_sum16(float x) {
    int t;
    t = __builtin_amdgcn_update_dpp(0, __float_as_int(x), 0xB1, 0xF, 0xF, true);  // quad_perm(1,0,3,2)
    x += __int_as_float(t);
    t = __builtin_amdgcn_update_dpp(0, __float_as_int(x), 0x4E, 0xF, 0xF, true);  // quad_perm(2,3,0,1)
    x += __int_as_float(t);
    t = __builtin_amdgcn_update_dpp(0, __float_as_int(x), 0x141, 0xF, 0xF, true); // row_half_mirror
    x += __int_as_float(t);
    t = __builtin_amdgcn_update_dpp(0, __float_as_int(x), 0x140, 0xF, 0xF, true); // row_mirror
    x += __int_as_float(t);
    return x;
}

// rank[e] = arrival index among edges sharing dst; deg accumulates counts
__global__ void rank_k(const int* __restrict__ dst, int* __restrict__ deg,
                       int* __restrict__ rank, int E) {
    int e = blockIdx.x * blockDim.x + threadIdx.x;
    if (e < E) rank[e] = atomicAdd(&deg[dst[e]], 1);
}

__global__ void scan1_k(const int* __restrict__ deg, int* __restrict__ off,
                        int* __restrict__ bsum, int N) {
    __shared__ int tmp[256];
    int i = blockIdx.x * 256 + threadIdx.x;
    int v = (i < N) ? deg[i] : 0;
    tmp[threadIdx.x] = v;
    __syncthreads();
#pragma unroll
    for (int s = 1; s < 256; s <<= 1) {
        int t = (threadIdx.x >= s) ? tmp[threadIdx.x - s] : 0;
        __syncthreads();
        tmp[threadIdx.x] += t;
        __syncthreads();
    }
    if (i < N) off[i] = tmp[threadIdx.x] - v;
    if (threadIdx.x == 255) bsum[blockIdx.x] = tmp[255];
}

__global__ void scan2_k(int* __restrict__ bsum, int nb) {
    __shared__ int tmp[512];
    int i = threadIdx.x;
    int v = (i < nb) ? bsum[i] : 0;
    tmp[i] = v;
    __syncthreads();
#pragma unroll
    for (int s = 1; s < 512; s <<= 1) {
        int t = (i >= s) ? tmp[i - s] : 0;
        __syncthreads();
        tmp[i] += t;
        __syncthreads();
    }
    if (i < nb) bsum[i] = tmp[i] - v;
}

__global__ void scan3_k(int* __restrict__ off, const int* __restrict__ bsum,
                        int N, int E) {
    int i = blockIdx.x * 256 + threadIdx.x;
    if (i < N) off[i] += bsum[blockIdx.x];
    if (i == 0) off[N] = E;
}

// atomic-free CSR fill using precomputed ranks
__global__ void fill2_k(const int* __restrict__ src, const int* __restrict__ dst,
                        const int* __restrict__ off, const int* __restrict__ rank,
                        int2* __restrict__ csr, int E) {
    int e = blockIdx.x * blockDim.x + threadIdx.x;
    if (e >= E) return;
    csr[off[dst[e]] + rank[e]] = make_int2(src[e], e);
}

// one wave per node: aggnf = mean of nf[neighbors] (butterfly), then
// h1[j] = relu(nf@W1s + aggnf@W1n + b1)[j] per lane, stored as bf16
__global__ __launch_bounds__(256, 8)
void aggh1f_k(const int* __restrict__ off, const int2* __restrict__ csr,
              const float* __restrict__ nf,
              const float* __restrict__ W1s, const float* __restrict__ W1n,
              const float* __restrict__ b1, unsigned short* __restrict__ h1s, int N) {
    int n = blockIdx.x * 4 + (threadIdx.x >> 6);
    if (n >= N) return;
    int l = threadIdx.x & 63;
    int s0 = off[n], s1 = off[n + 1];
    float4 a = {0.f, 0.f, 0.f, 0.f};
    for (int i = s0 + l; i < s1; i += 64) {
        float4 r = ((const float4*)nf)[csr[i].x];
        a.x += r.x; a.y += r.y; a.z += r.z; a.w += r.w;
    }
#pragma unroll
    for (int m = 1; m < 64; m <<= 1) {
        a.x += __shfl_xor(a.x, m);
        a.y += __shfl_xor(a.y, m);
        a.z += __shfl_xor(a.z, m);
        a.w += __shfl_xor(a.w, m);
    }
    float invd = 1.f / fmaxf((float)(s1 - s0), 1.f);
    a.x *= invd; a.y *= invd; a.z *= invd; a.w *= invd;
    float4 r = ((const float4*)nf)[n];
    float v = b1[l]
            + r.x * W1s[l] + r.y * W1s[64 + l] + r.z * W1s[128 + l] + r.w * W1s[192 + l]
            + a.x * W1n[l] + a.y * W1n[64 + l] + a.z * W1n[128 + l] + a.w * W1n[192 + l];
    h1s[(size_t)n * 64 + l] = f2bf(fmaxf(v, 0.f));
}

// one wave per node (4 nodes/block): aggh1b[n] = mean of bf16 h1 rows.
// lane l: slot g=l>>3, octet q=l&7 -> features 8q..8q+7 via uint4 loads.
// 16 rows in flight (two uint4 streams). Reduce across slots xor {8,16,32}.
__global__ __launch_bounds__(256, 8)
void gatherh1_k(const int* __restrict__ off, const int2* __restrict__ csr,
                const uint4* __restrict__ h1b4, uint4* __restrict__ ah1b4, int N) {
    int n = blockIdx.x * 4 + (threadIdx.x >> 6);
    if (n >= N) return;
    int l = threadIdx.x & 63;
    int g = l >> 3, q = l & 7;
    int s0 = off[n], s1 = off[n + 1];
    float a0 = 0.f, a1 = 0.f, a2 = 0.f, a3 = 0.f;
    float a4 = 0.f, a5 = 0.f, a6 = 0.f, a7 = 0.f;
    int i = s0;
    for (; i + 16 <= s1; i += 16) {
        int r0 = csr[i + g].x;
        int r1 = csr[i + 8 + g].x;
        uint4 v0 = h1b4[(size_t)r0 * 8 + q];
        uint4 v1 = h1b4[(size_t)r1 * 8 + q];
        a0 += bflo(v0.x) + bflo(v1.x); a1 += bfhi(v0.x) + bfhi(v1.x);
        a2 += bflo(v0.y) + bflo(v1.y); a3 += bfhi(v0.y) + bfhi(v1.y);
        a4 += bflo(v0.z) + bflo(v1.z); a5 += bfhi(v0.z) + bfhi(v1.z);
        a6 += bflo(v0.w) + bflo(v1.w); a7 += bfhi(v0.w) + bfhi(v1.w);
    }
    for (; i + 8 <= s1; i += 8) {
        int r = csr[i + g].x;
        uint4 v = h1b4[(size_t)r * 8 + q];
        a0 += bflo(v.x); a1 += bfhi(v.x);
        a2 += bflo(v.y); a3 += bfhi(v.y);
        a4 += bflo(v.z); a5 += bfhi(v.z);
        a6 += bflo(v.w); a7 += bfhi(v.w);
    }
    int rem = s1 - i;
    if (g < rem) {
        int r = csr[i + g].x;
        uint4 v = h1b4[(size_t)r * 8 + q];
        a0 += bflo(v.x); a1 += bfhi(v.x);
        a2 += bflo(v.y); a3 += bfhi(v.y);
        a4 += bflo(v.z); a5 += bfhi(v.z);
        a6 += bflo(v.w); a7 += bfhi(v.w);
    }
#pragma unroll
    for (int m = 8; m <= 32; m <<= 1) {
        a0 += __shfl_xor(a0, m); a1 += __shfl_xor(a1, m);
        a2 += __shfl_xor(a2, m); a3 += __shfl_xor(a3, m);
        a4 += __shfl_xor(a4, m); a5 += __shfl_xor(a5, m);
        a6 += __shfl_xor(a6, m); a7 += __shfl_xor(a7, m);
    }
    if (l < 8) {
        float invd = 1.f / fmaxf((float)(s1 - s0), 1.f);
        uint4 pk;
        pk.x = pack2bf(a0 * invd, a1 * invd);
        pk.y = pack2bf(a2 * invd, a3 * invd);
        pk.z = pack2bf(a4 * invd, a5 * invd);
        pk.w = pack2bf(a6 * invd, a7 * invd);
        ah1b4[(size_t)n * 8 + q] = pk;
    }
}

__device__ __forceinline__ void mac64(const float (*hT)[68], const float (*wt)[64],
                                      int rr, int cr, float acc[4][4]) {
#pragma unroll 8
    for (int k = 0; k < 64; ++k) {
        float4 a = *(const float4*)&hT[k][rr];
        float4 w = *(const float4*)&wt[k][cr];
        acc[0][0] = fmaf(a.x, w.x, acc[0][0]); acc[0][1] = fmaf(a.x, w.y, acc[0][1]);
        acc[0][2] = fmaf(a.x, w.z, acc[0][2]); acc[0][3] = fmaf(a.x, w.w, acc[0][3]);
        acc[1][0] = fmaf(a.y, w.x, acc[1][0]); acc[1][1] = fmaf(a.y, w.y, acc[1][1]);
        acc[1][2] = fmaf(a.y, w.z, acc[1][2]); acc[1][3] = fmaf(a.y, w.w, acc[1][3]);
        acc[2][0] = fmaf(a.z, w.x, acc[2][0]); acc[2][1] = fmaf(a.z, w.y, acc[2][1]);
        acc[2][2] = fmaf(a.z, w.z, acc[2][2]); acc[2][3] = fmaf(a.z, w.w, acc[2][3]);
        acc[3][0] = fmaf(a.w, w.x, acc[3][0]); acc[3][1] = fmaf(a.w, w.y, acc[3][1]);
        acc[3][2] = fmaf(a.w, w.z, acc[3][2]); acc[3][3] = fmaf(a.w, w.w, acc[3][3]);
    }
}

// ---------------------------------------------------------------------------
// Fused node MLP: h2 = relu(h1@W2s + aggh1@W2n + b2); hn = relu(h2@Wnp+bnp);
// ST(bf16) = hn @ Wbig (Wbig mapping computed inline from We1/Wl1).
// ---------------------------------------------------------------------------
__global__ __launch_bounds__(256, 4)
void node_mlp_k(const unsigned* __restrict__ h1b, const unsigned* __restrict__ ah1b,
                const float* __restrict__ W2s, const float* __restrict__ W2n,
                const float* __restrict__ b2, const float* __restrict__ Wnp,
                const float* __restrict__ bnp, const float* __restrict__ We1,
                const float* __restrict__ Wl1, unsigned short* __restrict__ ST, int N) {
    __shared__ __align__(16) float hT[64][68];
    __shared__ __align__(16) float wt[64][64];
    const int t = threadIdx.x;
    const int m0 = blockIdx.x * 64;
    const int cr = (t & 15) << 2, rr = (t >> 4) << 2;
    float acc[4][4] = {};

    // phase A1: self term from bf16 h1
#pragma unroll
    for (int it = 0; it < 8; ++it) {
        int u = it * 256 + t;
        int m = u >> 5, p = u & 31;
        int row = m0 + m;
        unsigned v = (row < N) ? h1b[(size_t)row * 32 + p] : 0u;
        hT[2 * p][m] = bflo(v);
        hT[2 * p + 1][m] = bfhi(v);
    }
#pragma unroll
    for (int it = 0; it < 16; ++it) {
        int k = it * 4 + (t >> 6), c = t & 63;
        wt[k][c] = W2s[k * 64 + c];
    }
    __syncthreads();
    mac64(hT, wt, rr, cr, acc);
    __syncthreads();

    // phase A2: neighbor term from bf16 aggh1
#pragma unroll
    for (int it = 0; it < 8; ++it) {
        int u = it * 256 + t;
        int m = u >> 5, p = u & 31;
        int row = m0 + m;
        unsigned v = (row < N) ? ah1b[(size_t)row * 32 + p] : 0u;
        hT[2 * p][m] = bflo(v);
        hT[2 * p + 1][m] = bfhi(v);
    }
#pragma unroll
    for (int it = 0; it < 16; ++it) {
        int k = it * 4 + (t >> 6), c = t & 63;
        wt[k][c] = W2n[k * 64 + c];
    }
    __syncthreads();
    mac64(hT, wt, rr, cr, acc);
    __syncthreads();

    // h2 -> hT (transposed), wt <- Wnp
#pragma unroll
    for (int i = 0; i < 4; ++i)
#pragma unroll
        for (int q = 0; q < 4; ++q)
            hT[cr + q][rr + i] = fmaxf(acc[i][q] + b2[cr + q], 0.f);
#pragma unroll
    for (int it = 0; it < 16; ++it) {
        int k = it * 4 + (t >> 6), c = t & 63;
        wt[k][c] = Wnp[k * 64 + c];
    }
    __syncthreads();
    float ac2[4][4] = {};
    mac64(hT, wt, rr, cr, ac2);
    __syncthreads();

    // hn -> hT (transposed)
#pragma unroll
    for (int i = 0; i < 4; ++i)
#pragma unroll
        for (int q = 0; q < 4; ++q)
            hT[cr + q][rr + i] = fmaxf(ac2[i][q] + bnp[cr + q], 0.f);
    __syncthreads();

    // 4 column phases of ST = hn @ Wbig (mapping inline)
    for (int cb = 0; cb < 4; ++cb) {
        if (cb) __syncthreads();
#pragma unroll
        for (int it = 0; it < 16; ++it) {
            int k = it * 4 + (t >> 6), c = t & 63;
            int cglob = cb * 64 + c;
            int half = cglob >> 7, cc = cglob & 127;
            int jj = cc >> 1, p = cc & 1;
            const float* W = p ? Wl1 : We1;
            wt[k][c] = W[(half * 64 + k) * 64 + jj];
        }
        __syncthreads();
        float ac3[4][4] = {};
        mac64(hT, wt, rr, cr, ac3);
#pragma unroll
        for (int i = 0; i < 4; ++i) {
            int row = m0 + rr + i;
            if (row >= N) continue;
            ushort4 pk;
            pk.x = f2bf(ac3[i][0]); pk.y = f2bf(ac3[i][1]);
            pk.z = f2bf(ac3[i][2]); pk.w = f2bf(ac3[i][3]);
            *(ushort4*)&ST[(size_t)row * 256 + cb * 64 + cr] = pk;
        }
    }
}

// ---------------------------------------------------------------------------
// Edge scorer: balanced grid-stride over 4-edge CSR chunks (no per-node
// tail). Quarter g handles chunk slot 4c+g; lane q covers j0=4q..4q+3.
// dst node recovered via dstarr[eid]; dst ST row gathered per chunk
// (same-node runs hit L1/L2). ef rows scalar via readlane + cndmask.
// 4-op DPP reductions. NO __launch_bounds__ (r9/r10 spill lesson).
// ---------------------------------------------------------------------------
__global__ void edge_k(const int2* __restrict__ csr, const int* __restrict__ dstarr,
                       const float* __restrict__ ef, const unsigned* __restrict__ ST32,
                       const float* __restrict__ We1, const float* __restrict__ be1,
                       const float* __restrict__ We2, const float* __restrict__ be2,
                       const float* __restrict__ Wl1, const float* __restrict__ bl1,
                       const float* __restrict__ Wl2, const float* __restrict__ bl2,
                       float* __restrict__ out, int E, int nwaves) {
    const int l = threadIdx.x & 63;
    const int g = l >> 4;            // edge slot within the 4-edge chunk
    const int q = l & 15;            // j-group
    const int j0 = q << 2;
    const int wid = blockIdx.x * (blockDim.x >> 6) + (threadIdx.x >> 6);

    float4 wet[5], wlt[5];
#pragma unroll
    for (int k = 0; k < 5; ++k) {
        wet[k] = *(const float4*)&We1[(128 + k) * 64 + j0];
        wlt[k] = *(const float4*)&Wl1[(128 + k) * 64 + j0];
    }
    const float4 vbe1 = *(const float4*)&be1[j0];
    const float4 vwe2 = *(const float4*)&We2[j0];
    const float4 vbl1 = *(const float4*)&bl1[j0];
    const float4 vwl2 = *(const float4*)&Wl2[j0];
    const float vbe2 = be2[0], vbl2 = bl2[0];

    const bool gb1 = (g & 1), gb2 = (g & 2);
    const int nch = (E + 3) >> 2;

    for (int c = wid; c < nch; c += nwaves) {
        int slot = c * 4 + g;
        bool act = slot < E;
        int2 se = csr[act ? slot : (E - 1)];          // quarter-uniform
        int dn = dstarr[se.y];                        // dst node id (4B, L2)
        uint4 pw = *(const uint4*)&ST32[(size_t)dn * 128 + 64 + j0];
        uint4 sw = *(const uint4*)&ST32[(size_t)se.x * 128 + j0];
        float4 t4 = {bflo(sw.x) + bflo(pw.x) + vbe1.x,
                     bflo(sw.y) + bflo(pw.y) + vbe1.y,
                     bflo(sw.z) + bflo(pw.z) + vbe1.z,
                     bflo(sw.w) + bflo(pw.w) + vbe1.w};
        float4 u4 = {bfhi(sw.x) + bfhi(pw.x), bfhi(sw.y) + bfhi(pw.y),
                     bfhi(sw.z) + bfhi(pw.z), bfhi(sw.w) + bfhi(pw.w)};
        // scalar ef rows for the 4 edges
        int e0 = __builtin_amdgcn_readlane(se.y, 0);
        int e1 = __builtin_amdgcn_readlane(se.y, 16);
        int e2 = __builtin_amdgcn_readlane(se.y, 32);
        int e3 = __builtin_amdgcn_readlane(se.y, 48);
        const float* p0 = ef + (size_t)e0 * 5;
        const float* p1 = ef + (size_t)e1 * 5;
        const float* p2 = ef + (size_t)e2 * 5;
        const float* p3 = ef + (size_t)e3 * 5;
#pragma unroll
        for (int k = 0; k < 5; ++k) {
            float a01 = gb1 ? p1[k] : p0[k];
            float a23 = gb1 ? p3[k] : p2[k];
            float ek  = gb2 ? a23 : a01;
            t4.x = fmaf(ek, wet[k].x, t4.x); t4.y = fmaf(ek, wet[k].y, t4.y);
            t4.z = fmaf(ek, wet[k].z, t4.z); t4.w = fmaf(ek, wet[k].w, t4.w);
            u4.x = fmaf(ek, wlt[k].x, u4.x); u4.y = fmaf(ek, wlt[k].y, u4.y);
            u4.z = fmaf(ek, wlt[k].z, u4.z); u4.w = fmaf(ek, wlt[k].w, u4.w);
        }
        float z = fast_tanh(t4.x) * vwe2.x + fast_tanh(t4.y) * vwe2.y
                + fast_tanh(t4.z) * vwe2.z + fast_tanh(t4.w) * vwe2.w;
        z = dpp_sum16(z);
        float w = fast_sigmoid(z + vbe2);
        float o = fmaxf(fmaf(w, u4.x, vbl1.x), 0.f) * vwl2.x
                + fmaxf(fmaf(w, u4.y, vbl1.y), 0.f) * vwl2.y
                + fmaxf(fmaf(w, u4.z, vbl1.z), 0.f) * vwl2.z
                + fmaxf(fmaf(w, u4.w, vbl1.w), 0.f) * vwl2.w;
        o = dpp_sum16(o);
        if (q == 0 && act) out[se.y] = o + vbl2;      // lanes 0,16,32,48
    }
}

extern "C" void kernel_launch(void* const* d_in, const int* in_sizes, int n_in,
                              void* d_out, int out_size, void* d_ws, size_t ws_size,
                              hipStream_t stream) {
    const float* nf  = (const float*)d_in[0];
    const float* ef  = (const float*)d_in[1];
    const int*   src = (const int*)d_in[2];
    const int*   dst = (const int*)d_in[3];
    const float* W1s = (const float*)d_in[4];
    const float* W1n = (const float*)d_in[5];
    const float* b1  = (const float*)d_in[6];
    const float* W2s = (const float*)d_in[7];
    const float* W2n = (const float*)d_in[8];
    const float* b2  = (const float*)d_in[9];
    const float* Wnp = (const float*)d_in[10];
    const float* bnp = (const float*)d_in[11];
    const float* We1 = (const float*)d_in[12];
    const float* be1 = (const float*)d_in[13];
    const float* We2 = (const float*)d_in[14];
    const float* be2 = (const float*)d_in[15];
    const float* Wl1 = (const float*)d_in[16];
    const float* bl1 = (const float*)d_in[17];
    const float* Wl2 = (const float*)d_in[18];
    const float* bl2 = (const float*)d_in[19];

    const int N = in_sizes[0] / 4;
    const int E = in_sizes[2];

    // ws layout (float units), peak ~274N = ~110 MB (proven budget ~128 MB):
    //  ST(bf16): [0, 128N)      written by node_mlp, read by edge_k
    //  ah1b:     [128N, 160N)   packed bf16 aggh1 (uint[32N])
    //  h1b:      [192N, 224N)   packed bf16 h1 (uint[32N])
    //  csr:      [224N, 256N)   int2[E]
    //  rank:     [256N, 272N)   int[E]
    //  deg:      [272N, 273N)   int[N]
    //  off:      [273N, 274N)+1 int[N+1]
    //  bsum:     off+N+1        int[512]
    float* wsf = (float*)d_ws;
    unsigned short* ST = (unsigned short*)wsf;
    unsigned* ah1b = (unsigned*)(wsf + (size_t)128 * N);
    unsigned* h1b  = (unsigned*)(wsf + (size_t)192 * N);
    int2* csr  = (int2*)(wsf + (size_t)224 * N);
    int*  rank = (int*)(wsf + (size_t)256 * N);
    int*  deg  = (int*)(wsf + (size_t)272 * N);
    int*  off  = deg + N;
    int*  bsum = off + N + 1;
    float* out = (float*)d_out;

    const int nblkN1 = (N + 255) / 256;
    const int nblkE  = (E + 255) / 256;
    const int nblkNw4 = (N + 3) / 4;     // 256-thread, 4 nodes
    const int gemmx  = (N + 63) / 64;
    const int EDGE_BLOCKS = 2048;
    const int nwaves = EDGE_BLOCKS * 4;

    // CSR build: single atomic pass + scan + atomic-free fill
    hipMemsetAsync(deg, 0, (size_t)N * sizeof(int), stream);
    rank_k<<<nblkE, 256, 0, stream>>>(dst, deg, rank, E);
    scan1_k<<<nblkN1, 256, 0, stream>>>(deg, off, bsum, N);
    scan2_k<<<1, 512, 0, stream>>>(bsum, nblkN1);
    scan3_k<<<nblkN1, 256, 0, stream>>>(off, bsum, N, E);
    fill2_k<<<nblkE, 256, 0, stream>>>(src, dst, off, rank, csr, E);

    // layer 1 (fused aggregate + h1, bf16 out)
    aggh1f_k<<<nblkNw4, 256, 0, stream>>>(off, csr, nf, W1s, W1n, b1,
                                          (unsigned short*)h1b, N);

    // layer 2 gather (bf16 out, uint4, 16 rows in flight)
    gatherh1_k<<<nblkNw4, 256, 0, stream>>>(off, csr, (const uint4*)h1b,
                                            (uint4*)ah1b, N);

    // fused node MLP -> bf16 ST table
    node_mlp_k<<<gemmx, 256, 0, stream>>>(h1b, ah1b, W2s, W2n, b2,
                                          Wnp, bnp, We1, Wl1, ST, N);

    // per-edge scoring (balanced chunks)
    edge_k<<<EDGE_BLOCKS, 256, 0, stream>>>(csr, dst, ef, (const unsigned*)ST,
                                            We1, be1, We2, be2, Wl1, bl1, Wl2, bl2,
                                            out, E, nwaves);
}

// Round 13
// 509.732 us; speedup vs baseline: 1.7216x; 1.0279x over previous
//
#include <hip/hip_runtime.h>
#include <math.h>

// ---------------------------------------------------------------------------
// EdgeClassifier: 2x SAGEConv(mean) -> per-node MLP -> edge scorer
//  * layer-1 agg: mean commutes with projection -> aggregate raw nf (4-dim),
//    fused with h1 compute (aggh1f_k), h1 stored packed bf16
//  * CSR: 1 atomic pass (rank) + scan + atomic-free scatter fill
//  * gatherh1: uint4 loads, 16 rows in flight; aggh1 stored packed bf16
//  * node_mlp_k: h1/aggh1(bf16) -> h2 -> hn -> bf16 ST in LDS
//  * edge_k: balanced grid-stride over 4-edge CSR chunks, TWO chunks
//    interleaved per iteration (2 independent load chains in flight --
//    round-6-proven ILP pattern); readlane ef + cndmask; DPP reductions;
//    NO launch_bounds (r9/r10: VGPR caps below the live set force scratch
//    spill -- WRITE 52 -> 120-576 MB; uncapped the compiler never spills)
// ---------------------------------------------------------------------------

__device__ __forceinline__ float fast_tanh(float x) {
    x = fminf(fmaxf(x, -15.f), 15.f);
    float e2 = __expf(2.f * x);
    return (e2 - 1.f) * __builtin_amdgcn_rcpf(e2 + 1.f);
}
__device__ __forceinline__ float fast_sigmoid(float x) {
    x = fminf(fmaxf(x, -60.f), 60.f);
    return __builtin_amdgcn_rcpf(1.f + __expf(-x));
}
__device__ __forceinline__ unsigned short f2bf(float f) {   // RNE
    unsigned u = __float_as_uint(f);
    u = u + 0x7FFFu + ((u >> 16) & 1u);
    return (unsigned short)(u >> 16);
}
__device__ __forceinline__ unsigned pack2bf(float lo, float hi) {
    return ((unsigned)f2bf(hi) << 16) | (unsigned)f2bf(lo);
}
__device__ __forceinline__ float bflo(unsigned u) { return __uint_as_float(u << 16); }
__device__ __forceinline__ float bfhi(unsigned u) { return __uint_as_float(u & 0xFFFF0000u); }

// 16-lane all-reduce sum, pure DPP (no LDS/DS)
__device__ __forceinline__ float dpp_sum16(float x) {
    int t;
    t = __builtin_amdgcn_update_dpp(0, __float_as_int(x), 0xB1, 0xF, 0xF, true);  // quad_perm(1,0,3,2)
    x += __int_as_float(t);
    t = __builtin_amdgcn_update_dpp(0, __float_as_int(x), 0x4E, 0xF, 0xF, true);  // quad_perm(2,3,0,1)
    x += __int_as_float(t);
    t = __builtin_amdgcn_update_dpp(0, __float_as_int(x), 0x141, 0xF, 0xF, true); // row_half_mirror
    x += __int_as_float(t);
    t = __builtin_amdgcn_update_dpp(0, __float_as_int(x), 0x140, 0xF, 0xF, true); // row_mirror
    x += __int_as_float(t);
    return x;
}

// rank[e] = arrival index among edges sharing dst; deg accumulates counts
__global__ void rank_k(const int* __restrict__ dst, int* __restrict__ deg,
                       int* __restrict__ rank, int E) {
    int e = blockIdx.x * blockDim.x + threadIdx.x;
    if (e < E) rank[e] = atomicAdd(&deg[dst[e]], 1);
}

__global__ void scan1_k(const int* __restrict__ deg, int* __restrict__ off,
                        int* __restrict__ bsum, int N) {
    __shared__ int tmp[256];
    int i = blockIdx.x * 256 + threadIdx.x;
    int v = (i < N) ? deg[i] : 0;
    tmp[threadIdx.x] = v;
    __syncthreads();
#pragma unroll
    for (int s = 1; s < 256; s <<= 1) {
        int t = (threadIdx.x >= s) ? tmp[threadIdx.x - s] : 0;
        __syncthreads();
        tmp[threadIdx.x] += t;
        __syncthreads();
    }
    if (i < N) off[i] = tmp[threadIdx.x] - v;
    if (threadIdx.x == 255) bsum[blockIdx.x] = tmp[255];
}

__global__ void scan2_k(int* __restrict__ bsum, int nb) {
    __shared__ int tmp[512];
    int i = threadIdx.x;
    int v = (i < nb) ? bsum[i] : 0;
    tmp[i] = v;
    __syncthreads();
#pragma unroll
    for (int s = 1; s < 512; s <<= 1) {
        int t = (i >= s) ? tmp[i - s] : 0;
        __syncthreads();
        tmp[i] += t;
        __syncthreads();
    }
    if (i < nb) bsum[i] = tmp[i] - v;
}

__global__ void scan3_k(int* __restrict__ off, const int* __restrict__ bsum,
                        int N, int E) {
    int i = blockIdx.x * 256 + threadIdx.x;
    if (i < N) off[i] += bsum[blockIdx.x];
    if (i == 0) off[N] = E;
}

// atomic-free CSR fill using precomputed ranks
__global__ void fill2_k(const int* __restrict__ src, const int* __restrict__ dst,
                        const int* __restrict__ off, const int* __restrict__ rank,
                        int2* __restrict__ csr, int E) {
    int e = blockIdx.x * blockDim.x + threadIdx.x;
    if (e >= E) return;
    csr[off[dst[e]] + rank[e]] = make_int2(src[e], e);
}

// one wave per node: aggnf = mean of nf[neighbors] (butterfly), then
// h1[j] = relu(nf@W1s + aggnf@W1n + b1)[j] per lane, stored as bf16
__global__ __launch_bounds__(256, 8)
void aggh1f_k(const int* __restrict__ off, const int2* __restrict__ csr,
              const float* __restrict__ nf,
              const float* __restrict__ W1s, const float* __restrict__ W1n,
              const float* __restrict__ b1, unsigned short* __restrict__ h1s, int N) {
    int n = blockIdx.x * 4 + (threadIdx.x >> 6);
    if (n >= N) return;
    int l = threadIdx.x & 63;
    int s0 = off[n], s1 = off[n + 1];
    float4 a = {0.f, 0.f, 0.f, 0.f};
    for (int i = s0 + l; i < s1; i += 64) {
        float4 r = ((const float4*)nf)[csr[i].x];
        a.x += r.x; a.y += r.y; a.z += r.z; a.w += r.w;
    }
#pragma unroll
    for (int m = 1; m < 64; m <<= 1) {
        a.x += __shfl_xor(a.x, m);
        a.y += __shfl_xor(a.y, m);
        a.z += __shfl_xor(a.z, m);
        a.w += __shfl_xor(a.w, m);
    }
    float invd = 1.f / fmaxf((float)(s1 - s0), 1.f);
    a.x *= invd; a.y *= invd; a.z *= invd; a.w *= invd;
    float4 r = ((const float4*)nf)[n];
    float v = b1[l]
            + r.x * W1s[l] + r.y * W1s[64 + l] + r.z * W1s[128 + l] + r.w * W1s[192 + l]
            + a.x * W1n[l] + a.y * W1n[64 + l] + a.z * W1n[128 + l] + a.w * W1n[192 + l];
    h1s[(size_t)n * 64 + l] = f2bf(fmaxf(v, 0.f));
}

// one wave per node (4 nodes/block): aggh1b[n] = mean of bf16 h1 rows.
// lane l: slot g=l>>3, octet q=l&7 -> features 8q..8q+7 via uint4 loads.
// 16 rows in flight (two uint4 streams). Reduce across slots xor {8,16,32}.
__global__ __launch_bounds__(256, 8)
void gatherh1_k(const int* __restrict__ off, const int2* __restrict__ csr,
                const uint4* __restrict__ h1b4, uint4* __restrict__ ah1b4, int N) {
    int n = blockIdx.x * 4 + (threadIdx.x >> 6);
    if (n >= N) return;
    int l = threadIdx.x & 63;
    int g = l >> 3, q = l & 7;
    int s0 = off[n], s1 = off[n + 1];
    float a0 = 0.f, a1 = 0.f, a2 = 0.f, a3 = 0.f;
    float a4 = 0.f, a5 = 0.f, a6 = 0.f, a7 = 0.f;
    int i = s0;
    for (; i + 16 <= s1; i += 16) {
        int r0 = csr[i + g].x;
        int r1 = csr[i + 8 + g].x;
        uint4 v0 = h1b4[(size_t)r0 * 8 + q];
        uint4 v1 = h1b4[(size_t)r1 * 8 + q];
        a0 += bflo(v0.x) + bflo(v1.x); a1 += bfhi(v0.x) + bfhi(v1.x);
        a2 += bflo(v0.y) + bflo(v1.y); a3 += bfhi(v0.y) + bfhi(v1.y);
        a4 += bflo(v0.z) + bflo(v1.z); a5 += bfhi(v0.z) + bfhi(v1.z);
        a6 += bflo(v0.w) + bflo(v1.w); a7 += bfhi(v0.w) + bfhi(v1.w);
    }
    for (; i + 8 <= s1; i += 8) {
        int r = csr[i + g].x;
        uint4 v = h1b4[(size_t)r * 8 + q];
        a0 += bflo(v.x); a1 += bfhi(v.x);
        a2 += bflo(v.y); a3 += bfhi(v.y);
        a4 += bflo(v.z); a5 += bfhi(v.z);
        a6 += bflo(v.w); a7 += bfhi(v.w);
    }
    int rem = s1 - i;
    if (g < rem) {
        int r = csr[i + g].x;
        uint4 v = h1b4[(size_t)r * 8 + q];
        a0 += bflo(v.x); a1 += bfhi(v.x);
        a2 += bflo(v.y); a3 += bfhi(v.y);
        a4 += bflo(v.z); a5 += bfhi(v.z);
        a6 += bflo(v.w); a7 += bfhi(v.w);
    }
#pragma unroll
    for (int m = 8; m <= 32; m <<= 1) {
        a0 += __shfl_xor(a0, m); a1 += __shfl_xor(a1, m);
        a2 += __shfl_xor(a2, m); a3 += __shfl_xor(a3, m);
        a4 += __shfl_xor(a4, m); a5 += __shfl_xor(a5, m);
        a6 += __shfl_xor(a6, m); a7 += __shfl_xor(a7, m);
    }
    if (l < 8) {
        float invd = 1.f / fmaxf((float)(s1 - s0), 1.f);
        uint4 pk;
        pk.x = pack2bf(a0 * invd, a1 * invd);
        pk.y = pack2bf(a2 * invd, a3 * invd);
        pk.z = pack2bf(a4 * invd, a5 * invd);
        pk.w = pack2bf(a6 * invd, a7 * invd);
        ah1b4[(size_t)n * 8 + q] = pk;
    }
}

__device__ __forceinline__ void mac64(const float (*hT)[68], const float (*wt)[64],
                                      int rr, int cr, float acc[4][4]) {
#pragma unroll 8
    for (int k = 0; k < 64; ++k) {
        float4 a = *(const float4*)&hT[k][rr];
        float4 w = *(const float4*)&wt[k][cr];
        acc[0][0] = fmaf(a.x, w.x, acc[0][0]); acc[0][1] = fmaf(a.x, w.y, acc[0][1]);
        acc[0][2] = fmaf(a.x, w.z, acc[0][2]); acc[0][3] = fmaf(a.x, w.w, acc[0][3]);
        acc[1][0] = fmaf(a.y, w.x, acc[1][0]); acc[1][1] = fmaf(a.y, w.y, acc[1][1]);
        acc[1][2] = fmaf(a.y, w.z, acc[1][2]); acc[1][3] = fmaf(a.y, w.w, acc[1][3]);
        acc[2][0] = fmaf(a.z, w.x, acc[2][0]); acc[2][1] = fmaf(a.z, w.y, acc[2][1]);
        acc[2][2] = fmaf(a.z, w.z, acc[2][2]); acc[2][3] = fmaf(a.z, w.w, acc[2][3]);
        acc[3][0] = fmaf(a.w, w.x, acc[3][0]); acc[3][1] = fmaf(a.w, w.y, acc[3][1]);
        acc[3][2] = fmaf(a.w, w.z, acc[3][2]); acc[3][3] = fmaf(a.w, w.w, acc[3][3]);
    }
}

// ---------------------------------------------------------------------------
// Fused node MLP: h2 = relu(h1@W2s + aggh1@W2n + b2); hn = relu(h2@Wnp+bnp);
// ST(bf16) = hn @ Wbig (Wbig mapping computed inline from We1/Wl1).
// ---------------------------------------------------------------------------
__global__ __launch_bounds__(256, 4)
void node_mlp_k(const unsigned* __restrict__ h1b, const unsigned* __restrict__ ah1b,
                const float* __restrict__ W2s, const float* __restrict__ W2n,
                const float* __restrict__ b2, const float* __restrict__ Wnp,
                const float* __restrict__ bnp, const float* __restrict__ We1,
                const float* __restrict__ Wl1, unsigned short* __restrict__ ST, int N) {
    __shared__ __align__(16) float hT[64][68];
    __shared__ __align__(16) float wt[64][64];
    const int t = threadIdx.x;
    const int m0 = blockIdx.x * 64;
    const int cr = (t & 15) << 2, rr = (t >> 4) << 2;
    float acc[4][4] = {};

    // phase A1: self term from bf16 h1
#pragma unroll
    for (int it = 0; it < 8; ++it) {
        int u = it * 256 + t;
        int m = u >> 5, p = u & 31;
        int row = m0 + m;
        unsigned v = (row < N) ? h1b[(size_t)row * 32 + p] : 0u;
        hT[2 * p][m] = bflo(v);
        hT[2 * p + 1][m] = bfhi(v);
    }
#pragma unroll
    for (int it = 0; it < 16; ++it) {
        int k = it * 4 + (t >> 6), c = t & 63;
        wt[k][c] = W2s[k * 64 + c];
    }
    __syncthreads();
    mac64(hT, wt, rr, cr, acc);
    __syncthreads();

    // phase A2: neighbor term from bf16 aggh1
#pragma unroll
    for (int it = 0; it < 8; ++it) {
        int u = it * 256 + t;
        int m = u >> 5, p = u & 31;
        int row = m0 + m;
        unsigned v = (row < N) ? ah1b[(size_t)row * 32 + p] : 0u;
        hT[2 * p][m] = bflo(v);
        hT[2 * p + 1][m] = bfhi(v);
    }
#pragma unroll
    for (int it = 0; it < 16; ++it) {
        int k = it * 4 + (t >> 6), c = t & 63;
        wt[k][c] = W2n[k * 64 + c];
    }
    __syncthreads();
    mac64(hT, wt, rr, cr, acc);
    __syncthreads();

    // h2 -> hT (transposed), wt <- Wnp
#pragma unroll
    for (int i = 0; i < 4; ++i)
#pragma unroll
        for (int q = 0; q < 4; ++q)
            hT[cr + q][rr + i] = fmaxf(acc[i][q] + b2[cr + q], 0.f);
#pragma unroll
    for (int it = 0; it < 16; ++it) {
        int k = it * 4 + (t >> 6), c = t & 63;
        wt[k][c] = Wnp[k * 64 + c];
    }
    __syncthreads();
    float ac2[4][4] = {};
    mac64(hT, wt, rr, cr, ac2);
    __syncthreads();

    // hn -> hT (transposed)
#pragma unroll
    for (int i = 0; i < 4; ++i)
#pragma unroll
        for (int q = 0; q < 4; ++q)
            hT[cr + q][rr + i] = fmaxf(ac2[i][q] + bnp[cr + q], 0.f);
    __syncthreads();

    // 4 column phases of ST = hn @ Wbig (mapping inline)
    for (int cb = 0; cb < 4; ++cb) {
        if (cb) __syncthreads();
#pragma unroll
        for (int it = 0; it < 16; ++it) {
            int k = it * 4 + (t >> 6), c = t & 63;
            int cglob = cb * 64 + c;
            int half = cglob >> 7, cc = cglob & 127;
            int jj = cc >> 1, p = cc & 1;
            const float* W = p ? Wl1 : We1;
            wt[k][c] = W[(half * 64 + k) * 64 + jj];
        }
        __syncthreads();
        float ac3[4][4] = {};
        mac64(hT, wt, rr, cr, ac3);
#pragma unroll
        for (int i = 0; i < 4; ++i) {
            int row = m0 + rr + i;
            if (row >= N) continue;
            ushort4 pk;
            pk.x = f2bf(ac3[i][0]); pk.y = f2bf(ac3[i][1]);
            pk.z = f2bf(ac3[i][2]); pk.w = f2bf(ac3[i][3]);
            *(ushort4*)&ST[(size_t)row * 256 + cb * 64 + cr] = pk;
        }
    }
}

// ---------------------------------------------------------------------------
// Edge scorer: balanced grid-stride, TWO 4-edge chunks interleaved per
// iteration (independent load chains -> 2x memory-level parallelism).
// Quarter g handles chunk slot 4c+g; lane q covers j0=4q..4q+3.
// dst node via dstarr[eid]; ef rows scalar via readlane + cndmask.
// 4-op DPP reductions. NO __launch_bounds__ (r9/r10 spill lesson).
// ---------------------------------------------------------------------------
__global__ void edge_k(const int2* __restrict__ csr, const int* __restrict__ dstarr,
                       const float* __restrict__ ef, const unsigned* __restrict__ ST32,
                       const float* __restrict__ We1, const float* __restrict__ be1,
                       const float* __restrict__ We2, const float* __restrict__ be2,
                       const float* __restrict__ Wl1, const float* __restrict__ bl1,
                       const float* __restrict__ Wl2, const float* __restrict__ bl2,
                       float* __restrict__ out, int E, int nwaves) {
    const int l = threadIdx.x & 63;
    const int g = l >> 4;            // edge slot within a 4-edge chunk
    const int q = l & 15;            // j-group
    const int j0 = q << 2;
    const int wid = blockIdx.x * (blockDim.x >> 6) + (threadIdx.x >> 6);

    float4 wet[5], wlt[5];
#pragma unroll
    for (int k = 0; k < 5; ++k) {
        wet[k] = *(const float4*)&We1[(128 + k) * 64 + j0];
        wlt[k] = *(const float4*)&Wl1[(128 + k) * 64 + j0];
    }
    const float4 vbe1 = *(const float4*)&be1[j0];
    const float4 vwe2 = *(const float4*)&We2[j0];
    const float4 vbl1 = *(const float4*)&bl1[j0];
    const float4 vwl2 = *(const float4*)&Wl2[j0];
    const float vbe2 = be2[0], vbl2 = bl2[0];

    const bool gb1 = (g & 1), gb2 = (g & 2);
    const int nch = (E + 3) >> 2;

    for (int c = wid; c < nch; c += 2 * nwaves) {
        int c2 = c + nwaves;
        bool hasB = c2 < nch;
        int slotA = c * 4 + g;
        int slotB = hasB ? c2 * 4 + g : 0;
        bool actA = slotA < E;
        bool actB = hasB && slotB < E;
        // two independent chains: both csr, then both dstarr, then 4 gathers
        int2 seA = csr[actA ? slotA : 0];
        int2 seB = csr[actB ? slotB : 0];
        int dnA = dstarr[seA.y];
        int dnB = dstarr[seB.y];
        uint4 pwA = *(const uint4*)&ST32[(size_t)dnA * 128 + 64 + j0];
        uint4 swA = *(const uint4*)&ST32[(size_t)seA.x * 128 + j0];
        uint4 pwB = *(const uint4*)&ST32[(size_t)dnB * 128 + 64 + j0];
        uint4 swB = *(const uint4*)&ST32[(size_t)seB.x * 128 + j0];

        // ---- chunk A ----
        {
            float4 t4 = {bflo(swA.x) + bflo(pwA.x) + vbe1.x,
                         bflo(swA.y) + bflo(pwA.y) + vbe1.y,
                         bflo(swA.z) + bflo(pwA.z) + vbe1.z,
                         bflo(swA.w) + bflo(pwA.w) + vbe1.w};
            float4 u4 = {bfhi(swA.x) + bfhi(pwA.x), bfhi(swA.y) + bfhi(pwA.y),
                         bfhi(swA.z) + bfhi(pwA.z), bfhi(swA.w) + bfhi(pwA.w)};
            int e0 = __builtin_amdgcn_readlane(seA.y, 0);
            int e1 = __builtin_amdgcn_readlane(seA.y, 16);
            int e2 = __builtin_amdgcn_readlane(seA.y, 32);
            int e3 = __builtin_amdgcn_readlane(seA.y, 48);
            const float* p0 = ef + (size_t)e0 * 5;
            const float* p1 = ef + (size_t)e1 * 5;
            const float* p2 = ef + (size_t)e2 * 5;
            const float* p3 = ef + (size_t)e3 * 5;
#pragma unroll
            for (int k = 0; k < 5; ++k) {
                float a01 = gb1 ? p1[k] : p0[k];
                float a23 = gb1 ? p3[k] : p2[k];
                float ek  = gb2 ? a23 : a01;
                t4.x = fmaf(ek, wet[k].x, t4.x); t4.y = fmaf(ek, wet[k].y, t4.y);
                t4.z = fmaf(ek, wet[k].z, t4.z); t4.w = fmaf(ek, wet[k].w, t4.w);
                u4.x = fmaf(ek, wlt[k].x, u4.x); u4.y = fmaf(ek, wlt[k].y, u4.y);
                u4.z = fmaf(ek, wlt[k].z, u4.z); u4.w = fmaf(ek, wlt[k].w, u4.w);
            }
            float z = fast_tanh(t4.x) * vwe2.x + fast_tanh(t4.y) * vwe2.y
                    + fast_tanh(t4.z) * vwe2.z + fast_tanh(t4.w) * vwe2.w;
            z = dpp_sum16(z);
            float w = fast_sigmoid(z + vbe2);
            float o = fmaxf(fmaf(w, u4.x, vbl1.x), 0.f) * vwl2.x
                    + fmaxf(fmaf(w, u4.y, vbl1.y), 0.f) * vwl2.y
                    + fmaxf(fmaf(w, u4.z, vbl1.z), 0.f) * vwl2.z
                    + fmaxf(fmaf(w, u4.w, vbl1.w), 0.f) * vwl2.w;
            o = dpp_sum16(o);
            if (q == 0 && actA) out[seA.y] = o + vbl2;
        }
        // ---- chunk B ----
        {
            float4 t4 = {bflo(swB.x) + bflo(pwB.x) + vbe1.x,
                         bflo(swB.y) + bflo(pwB.y) + vbe1.y,
                         bflo(swB.z) + bflo(pwB.z) + vbe1.z,
                         bflo(swB.w) + bflo(pwB.w) + vbe1.w};
            float4 u4 = {bfhi(swB.x) + bfhi(pwB.x), bfhi(swB.y) + bfhi(pwB.y),
                         bfhi(swB.z) + bfhi(pwB.z), bfhi(swB.w) + bfhi(pwB.w)};
            int e0 = __builtin_amdgcn_readlane(seB.y, 0);
            int e1 = __builtin_amdgcn_readlane(seB.y, 16);
            int e2 = __builtin_amdgcn_readlane(seB.y, 32);
            int e3 = __builtin_amdgcn_readlane(seB.y, 48);
            const float* p0 = ef + (size_t)e0 * 5;
            const float* p1 = ef + (size_t)e1 * 5;
            const float* p2 = ef + (size_t)e2 * 5;
            const float* p3 = ef + (size_t)e3 * 5;
#pragma unroll
            for (int k = 0; k < 5; ++k) {
                float a01 = gb1 ? p1[k] : p0[k];
                float a23 = gb1 ? p3[k] : p2[k];
                float ek  = gb2 ? a23 : a01;
                t4.x = fmaf(ek, wet[k].x, t4.x); t4.y = fmaf(ek, wet[k].y, t4.y);
                t4.z = fmaf(ek, wet[k].z, t4.z); t4.w = fmaf(ek, wet[k].w, t4.w);
                u4.x = fmaf(ek, wlt[k].x, u4.x); u4.y = fmaf(ek, wlt[k].y, u4.y);
                u4.z = fmaf(ek, wlt[k].z, u4.z); u4.w = fmaf(ek, wlt[k].w, u4.w);
            }
            float z = fast_tanh(t4.x) * vwe2.x + fast_tanh(t4.y) * vwe2.y
                    + fast_tanh(t4.z) * vwe2.z + fast_tanh(t4.w) * vwe2.w;
            z = dpp_sum16(z);
            float w = fast_sigmoid(z + vbe2);
            float o = fmaxf(fmaf(w, u4.x, vbl1.x), 0.f) * vwl2.x
                    + fmaxf(fmaf(w, u4.y, vbl1.y), 0.f) * vwl2.y
                    + fmaxf(fmaf(w, u4.z, vbl1.z), 0.f) * vwl2.z
                    + fmaxf(fmaf(w, u4.w, vbl1.w), 0.f) * vwl2.w;
            o = dpp_sum16(o);
            if (q == 0 && actB) out[seB.y] = o + vbl2;
        }
    }
}

extern "C" void kernel_launch(void* const* d_in, const int* in_sizes, int n_in,
                              void* d_out, int out_size, void* d_ws, size_t ws_size,
                              hipStream_t stream) {
    const float* nf  = (const float*)d_in[0];
    const float* ef  = (const float*)d_in[1];
    const int*   src = (const int*)d_in[2];
    const int*   dst = (const int*)d_in[3];
    const float* W1s = (const float*)d_in[4];
    const float* W1n = (const float*)d_in[5];
    const float* b1  = (const float*)d_in[6];
    const float* W2s = (const float*)d_in[7];
    const float* W2n = (const float*)d_in[8];
    const float* b2  = (const float*)d_in[9];
    const float* Wnp = (const float*)d_in[10];
    const float* bnp = (const float*)d_in[11];
    const float* We1 = (const float*)d_in[12];
    const float* be1 = (const float*)d_in[13];
    const float* We2 = (const float*)d_in[14];
    const float* be2 = (const float*)d_in[15];
    const float* Wl1 = (const float*)d_in[16];
    const float* bl1 = (const float*)d_in[17];
    const float* Wl2 = (const float*)d_in[18];
    const float* bl2 = (const float*)d_in[19];

    const int N = in_sizes[0] / 4;
    const int E = in_sizes[2];

    // ws layout (float units), peak ~274N = ~110 MB (proven budget ~128 MB):
    //  ST(bf16): [0, 128N)      written by node_mlp, read by edge_k
    //  ah1b:     [128N, 160N)   packed bf16 aggh1 (uint[32N])
    //  h1b:      [192N, 224N)   packed bf16 h1 (uint[32N])
    //  csr:      [224N, 256N)   int2[E]
    //  rank:     [256N, 272N)   int[E]
    //  deg:      [272N, 273N)   int[N]
    //  off:      [273N, 274N)+1 int[N+1]
    //  bsum:     off+N+1        int[512]
    float* wsf = (float*)d_ws;
    unsigned short* ST = (unsigned short*)wsf;
    unsigned* ah1b = (unsigned*)(wsf + (size_t)128 * N);
    unsigned* h1b  = (unsigned*)(wsf + (size_t)192 * N);
    int2* csr  = (int2*)(wsf + (size_t)224 * N);
    int*  rank = (int*)(wsf + (size_t)256 * N);
    int*  deg  = (int*)(wsf + (size_t)272 * N);
    int*  off  = deg + N;
    int*  bsum = off + N + 1;
    float* out = (float*)d_out;

    const int nblkN1 = (N + 255) / 256;
    const int nblkE  = (E + 255) / 256;
    const int nblkNw4 = (N + 3) / 4;     // 256-thread, 4 nodes
    const int gemmx  = (N + 63) / 64;
    const int EDGE_BLOCKS = 2048;
    const int nwaves = EDGE_BLOCKS * 4;

    // CSR build: single atomic pass + scan + atomic-free fill
    hipMemsetAsync(deg, 0, (size_t)N * sizeof(int), stream);
    rank_k<<<nblkE, 256, 0, stream>>>(dst, deg, rank, E);
    scan1_k<<<nblkN1, 256, 0, stream>>>(deg, off, bsum, N);
    scan2_k<<<1, 512, 0, stream>>>(bsum, nblkN1);
    scan3_k<<<nblkN1, 256, 0, stream>>>(off, bsum, N, E);
    fill2_k<<<nblkE, 256, 0, stream>>>(src, dst, off, rank, csr, E);

    // layer 1 (fused aggregate + h1, bf16 out)
    aggh1f_k<<<nblkNw4, 256, 0, stream>>>(off, csr, nf, W1s, W1n, b1,
                                          (unsigned short*)h1b, N);

    // layer 2 gather (bf16 out, uint4, 16 rows in flight)
    gatherh1_k<<<nblkNw4, 256, 0, stream>>>(off, csr, (const uint4*)h1b,
                                            (uint4*)ah1b, N);

    // fused node MLP -> bf16 ST table
    node_mlp_k<<<gemmx, 256, 0, stream>>>(h1b, ah1b, W2s, W2n, b2,
                                          Wnp, bnp, We1, Wl1, ST, N);

    // per-edge scoring (balanced chunks, 2-way ILP)
    edge_k<<<EDGE_BLOCKS, 256, 0, stream>>>(csr, dst, ef, (const unsigned*)ST,
                                            We1, be1, We2, be2, Wl1, bl1, Wl2, bl2,
                                            out, E, nwaves);
}

// Round 14
// 499.456 us; speedup vs baseline: 1.7571x; 1.0206x over previous
//
#include <hip/hip_runtime.h>
#include <math.h>

// ---------------------------------------------------------------------------
// EdgeClassifier: 2x SAGEConv(mean) -> per-node MLP -> edge scorer
//  * layer-1 agg: mean commutes with projection -> aggregate raw nf (4-dim),
//    fused with h1 compute; quarter-wave (16 lanes) per node, DPP all-reduce
//  * CSR: 1 atomic pass (rank) + scan + atomic-free scatter fill
//  * gatherh1: uint4 loads, 16 rows in flight; aggh1 stored packed bf16
//  * node_mlp_k: h1/aggh1(bf16) -> h2 -> hn -> bf16 ST in LDS
//  * edge_k: balanced grid-stride, 2x 4-edge chunks interleaved (ILP);
//    per-quarter broadcast ef loads (same-address HW broadcast, no cndmask);
//    DPP reductions; NO launch_bounds (r9/r10: VGPR caps below the live set
//    force scratch spill -- WRITE 52 -> 120-576 MB; uncapped never spills)
// ---------------------------------------------------------------------------

__device__ __forceinline__ float fast_tanh(float x) {
    x = fminf(fmaxf(x, -15.f), 15.f);
    float e2 = __expf(2.f * x);
    return (e2 - 1.f) * __builtin_amdgcn_rcpf(e2 + 1.f);
}
__device__ __forceinline__ float fast_sigmoid(float x) {
    x = fminf(fmaxf(x, -60.f), 60.f);
    return __builtin_amdgcn_rcpf(1.f + __expf(-x));
}
__device__ __forceinline__ unsigned short f2bf(float f) {   // RNE
    unsigned u = __float_as_uint(f);
    u = u + 0x7FFFu + ((u >> 16) & 1u);
    return (unsigned short)(u >> 16);
}
__device__ __forceinline__ unsigned pack2bf(float lo, float hi) {
    return ((unsigned)f2bf(hi) << 16) | (unsigned)f2bf(lo);
}
__device__ __forceinline__ float bflo(unsigned u) { return __uint_as_float(u << 16); }
__device__ __forceinline__ float bfhi(unsigned u) { return __uint_as_float(u & 0xFFFF0000u); }

// 16-lane all-reduce sum, pure DPP (no LDS/DS); reduces within 16-lane rows
__device__ __forceinline__ float dpp_sum16(float x) {
    int t;
    t = __builtin_amdgcn_update_dpp(0, __float_as_int(x), 0xB1, 0xF, 0xF, true);  // quad_perm(1,0,3,2)
    x += __int_as_float(t);
    t = __builtin_amdgcn_update_dpp(0, __float_as_int(x), 0x4E, 0xF, 0xF, true);  // quad_perm(2,3,0,1)
    x += __int_as_float(t);
    t = __builtin_amdgcn_update_dpp(0, __float_as_int(x), 0x141, 0xF, 0xF, true); // row_half_mirror
    x += __int_as_float(t);
    t = __builtin_amdgcn_update_dpp(0, __float_as_int(x), 0x140, 0xF, 0xF, true); // row_mirror
    x += __int_as_float(t);
    return x;
}

// rank[e] = arrival index among edges sharing dst; deg accumulates counts
__global__ void rank_k(const int* __restrict__ dst, int* __restrict__ deg,
                       int* __restrict__ rank, int E) {
    int e = blockIdx.x * blockDim.x + threadIdx.x;
    if (e < E) rank[e] = atomicAdd(&deg[dst[e]], 1);
}

__global__ void scan1_k(const int* __restrict__ deg, int* __restrict__ off,
                        int* __restrict__ bsum, int N) {
    __shared__ int tmp[256];
    int i = blockIdx.x * 256 + threadIdx.x;
    int v = (i < N) ? deg[i] : 0;
    tmp[threadIdx.x] = v;
    __syncthreads();
#pragma unroll
    for (int s = 1; s < 256; s <<= 1) {
        int t = (threadIdx.x >= s) ? tmp[threadIdx.x - s] : 0;
        __syncthreads();
        tmp[threadIdx.x] += t;
        __syncthreads();
    }
    if (i < N) off[i] = tmp[threadIdx.x] - v;
    if (threadIdx.x == 255) bsum[blockIdx.x] = tmp[255];
}

__global__ void scan2_k(int* __restrict__ bsum, int nb) {
    __shared__ int tmp[512];
    int i = threadIdx.x;
    int v = (i < nb) ? bsum[i] : 0;
    tmp[i] = v;
    __syncthreads();
#pragma unroll
    for (int s = 1; s < 512; s <<= 1) {
        int t = (i >= s) ? tmp[i - s] : 0;
        __syncthreads();
        tmp[i] += t;
        __syncthreads();
    }
    if (i < nb) bsum[i] = tmp[i] - v;
}

__global__ void scan3_k(int* __restrict__ off, const int* __restrict__ bsum,
                        int N, int E) {
    int i = blockIdx.x * 256 + threadIdx.x;
    if (i < N) off[i] += bsum[blockIdx.x];
    if (i == 0) off[N] = E;
}

// atomic-free CSR fill using precomputed ranks
__global__ void fill2_k(const int* __restrict__ src, const int* __restrict__ dst,
                        const int* __restrict__ off, const int* __restrict__ rank,
                        int2* __restrict__ csr, int E) {
    int e = blockIdx.x * blockDim.x + threadIdx.x;
    if (e >= E) return;
    csr[off[dst[e]] + rank[e]] = make_int2(src[e], e);
}

// quarter-wave (16 lanes) per node, 16 nodes/block: aggnf = mean of
// nf[neighbors] (stride-16 gather + DPP-16 all-reduce), then lane q
// computes h1 cols j=4q..4q+3 = relu(nf@W1s + aggnf@W1n + b1), packed bf16.
__global__ __launch_bounds__(256, 8)
void aggh1f_k(const int* __restrict__ off, const int2* __restrict__ csr,
              const float* __restrict__ nf,
              const float* __restrict__ W1s, const float* __restrict__ W1n,
              const float* __restrict__ b1, unsigned* __restrict__ h1b, int N) {
    int n = blockIdx.x * 16 + (threadIdx.x >> 4);
    if (n >= N) return;
    int q = threadIdx.x & 15;
    int s0 = off[n], s1 = off[n + 1];
    float4 a = {0.f, 0.f, 0.f, 0.f};
    for (int i = s0 + q; i < s1; i += 16) {
        float4 r = ((const float4*)nf)[csr[i].x];
        a.x += r.x; a.y += r.y; a.z += r.z; a.w += r.w;
    }
    a.x = dpp_sum16(a.x);
    a.y = dpp_sum16(a.y);
    a.z = dpp_sum16(a.z);
    a.w = dpp_sum16(a.w);
    float invd = 1.f / fmaxf((float)(s1 - s0), 1.f);
    a.x *= invd; a.y *= invd; a.z *= invd; a.w *= invd;
    float4 r = ((const float4*)nf)[n];
    const int j0 = q << 2;
    float4 acc = *(const float4*)&b1[j0];
#pragma unroll
    for (int k = 0; k < 4; ++k) {
        float rk = (k == 0) ? r.x : (k == 1) ? r.y : (k == 2) ? r.z : r.w;
        float ak = (k == 0) ? a.x : (k == 1) ? a.y : (k == 2) ? a.z : a.w;
        float4 ws = *(const float4*)&W1s[k * 64 + j0];
        float4 wn = *(const float4*)&W1n[k * 64 + j0];
        acc.x = fmaf(rk, ws.x, acc.x); acc.y = fmaf(rk, ws.y, acc.y);
        acc.z = fmaf(rk, ws.z, acc.z); acc.w = fmaf(rk, ws.w, acc.w);
        acc.x = fmaf(ak, wn.x, acc.x); acc.y = fmaf(ak, wn.y, acc.y);
        acc.z = fmaf(ak, wn.z, acc.z); acc.w = fmaf(ak, wn.w, acc.w);
    }
    uint2 pk;
    pk.x = pack2bf(fmaxf(acc.x, 0.f), fmaxf(acc.y, 0.f));
    pk.y = pack2bf(fmaxf(acc.z, 0.f), fmaxf(acc.w, 0.f));
    *(uint2*)&h1b[(size_t)n * 32 + (q << 1)] = pk;
}

// one wave per node (4 nodes/block): aggh1b[n] = mean of bf16 h1 rows.
// lane l: slot g=l>>3, octet q=l&7 -> features 8q..8q+7 via uint4 loads.
// 16 rows in flight (two uint4 streams). Reduce across slots xor {8,16,32}.
__global__ __launch_bounds__(256, 8)
void gatherh1_k(const int* __restrict__ off, const int2* __restrict__ csr,
                const uint4* __restrict__ h1b4, uint4* __restrict__ ah1b4, int N) {
    int n = blockIdx.x * 4 + (threadIdx.x >> 6);
    if (n >= N) return;
    int l = threadIdx.x & 63;
    int g = l >> 3, q = l & 7;
    int s0 = off[n], s1 = off[n + 1];
    float a0 = 0.f, a1 = 0.f, a2 = 0.f, a3 = 0.f;
    float a4 = 0.f, a5 = 0.f, a6 = 0.f, a7 = 0.f;
    int i = s0;
    for (; i + 16 <= s1; i += 16) {
        int r0 = csr[i + g].x;
        int r1 = csr[i + 8 + g].x;
        uint4 v0 = h1b4[(size_t)r0 * 8 + q];
        uint4 v1 = h1b4[(size_t)r1 * 8 + q];
        a0 += bflo(v0.x) + bflo(v1.x); a1 += bfhi(v0.x) + bfhi(v1.x);
        a2 += bflo(v0.y) + bflo(v1.y); a3 += bfhi(v0.y) + bfhi(v1.y);
        a4 += bflo(v0.z) + bflo(v1.z); a5 += bfhi(v0.z) + bfhi(v1.z);
        a6 += bflo(v0.w) + bflo(v1.w); a7 += bfhi(v0.w) + bfhi(v1.w);
    }
    for (; i + 8 <= s1; i += 8) {
        int r = csr[i + g].x;
        uint4 v = h1b4[(size_t)r * 8 + q];
        a0 += bflo(v.x); a1 += bfhi(v.x);
        a2 += bflo(v.y); a3 += bfhi(v.y);
        a4 += bflo(v.z); a5 += bfhi(v.z);
        a6 += bflo(v.w); a7 += bfhi(v.w);
    }
    int rem = s1 - i;
    if (g < rem) {
        int r = csr[i + g].x;
        uint4 v = h1b4[(size_t)r * 8 + q];
        a0 += bflo(v.x); a1 += bfhi(v.x);
        a2 += bflo(v.y); a3 += bfhi(v.y);
        a4 += bflo(v.z); a5 += bfhi(v.z);
        a6 += bflo(v.w); a7 += bfhi(v.w);
    }
#pragma unroll
    for (int m = 8; m <= 32; m <<= 1) {
        a0 += __shfl_xor(a0, m); a1 += __shfl_xor(a1, m);
        a2 += __shfl_xor(a2, m); a3 += __shfl_xor(a3, m);
        a4 += __shfl_xor(a4, m); a5 += __shfl_xor(a5, m);
        a6 += __shfl_xor(a6, m); a7 += __shfl_xor(a7, m);
    }
    if (l < 8) {
        float invd = 1.f / fmaxf((float)(s1 - s0), 1.f);
        uint4 pk;
        pk.x = pack2bf(a0 * invd, a1 * invd);
        pk.y = pack2bf(a2 * invd, a3 * invd);
        pk.z = pack2bf(a4 * invd, a5 * invd);
        pk.w = pack2bf(a6 * invd, a7 * invd);
        ah1b4[(size_t)n * 8 + q] = pk;
    }
}

__device__ __forceinline__ void mac64(const float (*hT)[68], const float (*wt)[64],
                                      int rr, int cr, float acc[4][4]) {
#pragma unroll 8
    for (int k = 0; k < 64; ++k) {
        float4 a = *(const float4*)&hT[k][rr];
        float4 w = *(const float4*)&wt[k][cr];
        acc[0][0] = fmaf(a.x, w.x, acc[0][0]); acc[0][1] = fmaf(a.x, w.y, acc[0][1]);
        acc[0][2] = fmaf(a.x, w.z, acc[0][2]); acc[0][3] = fmaf(a.x, w.w, acc[0][3]);
        acc[1][0] = fmaf(a.y, w.x, acc[1][0]); acc[1][1] = fmaf(a.y, w.y, acc[1][1]);
        acc[1][2] = fmaf(a.y, w.z, acc[1][2]); acc[1][3] = fmaf(a.y, w.w, acc[1][3]);
        acc[2][0] = fmaf(a.z, w.x, acc[2][0]); acc[2][1] = fmaf(a.z, w.y, acc[2][1]);
        acc[2][2] = fmaf(a.z, w.z, acc[2][2]); acc[2][3] = fmaf(a.z, w.w, acc[2][3]);
        acc[3][0] = fmaf(a.w, w.x, acc[3][0]); acc[3][1] = fmaf(a.w, w.y, acc[3][1]);
        acc[3][2] = fmaf(a.w, w.z, acc[3][2]); acc[3][3] = fmaf(a.w, w.w, acc[3][3]);
    }
}

// ---------------------------------------------------------------------------
// Fused node MLP: h2 = relu(h1@W2s + aggh1@W2n + b2); hn = relu(h2@Wnp+bnp);
// ST(bf16) = hn @ Wbig (Wbig mapping computed inline from We1/Wl1).
// ---------------------------------------------------------------------------
__global__ __launch_bounds__(256, 4)
void node_mlp_k(const unsigned* __restrict__ h1b, const unsigned* __restrict__ ah1b,
                const float* __restrict__ W2s, const float* __restrict__ W2n,
                const float* __restrict__ b2, const float* __restrict__ Wnp,
                const float* __restrict__ bnp, const float* __restrict__ We1,
                const float* __restrict__ Wl1, unsigned short* __restrict__ ST, int N) {
    __shared__ __align__(16) float hT[64][68];
    __shared__ __align__(16) float wt[64][64];
    const int t = threadIdx.x;
    const int m0 = blockIdx.x * 64;
    const int cr = (t & 15) << 2, rr = (t >> 4) << 2;
    float acc[4][4] = {};

    // phase A1: self term from bf16 h1
#pragma unroll
    for (int it = 0; it < 8; ++it) {
        int u = it * 256 + t;
        int m = u >> 5, p = u & 31;
        int row = m0 + m;
        unsigned v = (row < N) ? h1b[(size_t)row * 32 + p] : 0u;
        hT[2 * p][m] = bflo(v);
        hT[2 * p + 1][m] = bfhi(v);
    }
#pragma unroll
    for (int it = 0; it < 16; ++it) {
        int k = it * 4 + (t >> 6), c = t & 63;
        wt[k][c] = W2s[k * 64 + c];
    }
    __syncthreads();
    mac64(hT, wt, rr, cr, acc);
    __syncthreads();

    // phase A2: neighbor term from bf16 aggh1
#pragma unroll
    for (int it = 0; it < 8; ++it) {
        int u = it * 256 + t;
        int m = u >> 5, p = u & 31;
        int row = m0 + m;
        unsigned v = (row < N) ? ah1b[(size_t)row * 32 + p] : 0u;
        hT[2 * p][m] = bflo(v);
        hT[2 * p + 1][m] = bfhi(v);
    }
#pragma unroll
    for (int it = 0; it < 16; ++it) {
        int k = it * 4 + (t >> 6), c = t & 63;
        wt[k][c] = W2n[k * 64 + c];
    }
    __syncthreads();
    mac64(hT, wt, rr, cr, acc);
    __syncthreads();

    // h2 -> hT (transposed), wt <- Wnp
#pragma unroll
    for (int i = 0; i < 4; ++i)
#pragma unroll
        for (int q = 0; q < 4; ++q)
            hT[cr + q][rr + i] = fmaxf(acc[i][q] + b2[cr + q], 0.f);
#pragma unroll
    for (int it = 0; it < 16; ++it) {
        int k = it * 4 + (t >> 6), c = t & 63;
        wt[k][c] = Wnp[k * 64 + c];
    }
    __syncthreads();
    float ac2[4][4] = {};
    mac64(hT, wt, rr, cr, ac2);
    __syncthreads();

    // hn -> hT (transposed)
#pragma unroll
    for (int i = 0; i < 4; ++i)
#pragma unroll
        for (int q = 0; q < 4; ++q)
            hT[cr + q][rr + i] = fmaxf(ac2[i][q] + bnp[cr + q], 0.f);
    __syncthreads();

    // 4 column phases of ST = hn @ Wbig (mapping inline)
    for (int cb = 0; cb < 4; ++cb) {
        if (cb) __syncthreads();
#pragma unroll
        for (int it = 0; it < 16; ++it) {
            int k = it * 4 + (t >> 6), c = t & 63;
            int cglob = cb * 64 + c;
            int half = cglob >> 7, cc = cglob & 127;
            int jj = cc >> 1, p = cc & 1;
            const float* W = p ? Wl1 : We1;
            wt[k][c] = W[(half * 64 + k) * 64 + jj];
        }
        __syncthreads();
        float ac3[4][4] = {};
        mac64(hT, wt, rr, cr, ac3);
#pragma unroll
        for (int i = 0; i < 4; ++i) {
            int row = m0 + rr + i;
            if (row >= N) continue;
            ushort4 pk;
            pk.x = f2bf(ac3[i][0]); pk.y = f2bf(ac3[i][1]);
            pk.z = f2bf(ac3[i][2]); pk.w = f2bf(ac3[i][3]);
            *(ushort4*)&ST[(size_t)row * 256 + cb * 64 + cr] = pk;
        }
    }
}

// ---------------------------------------------------------------------------
// Edge scorer: balanced grid-stride, TWO 4-edge chunks interleaved per
// iteration. Quarter g handles chunk slot 4c+g; lane q covers j0=4q..4q+3.
// dst node via dstarr[eid]; ef via per-quarter same-address loads (HW
// broadcast -- no readlane/cndmask; named scalars only, no local arrays).
// 4-op DPP reductions. NO __launch_bounds__ (r9/r10 spill lesson).
// ---------------------------------------------------------------------------
__global__ void edge_k(const int2* __restrict__ csr, const int* __restrict__ dstarr,
                       const float* __restrict__ ef, const unsigned* __restrict__ ST32,
                       const float* __restrict__ We1, const float* __restrict__ be1,
                       const float* __restrict__ We2, const float* __restrict__ be2,
                       const float* __restrict__ Wl1, const float* __restrict__ bl1,
                       const float* __restrict__ Wl2, const float* __restrict__ bl2,
                       float* __restrict__ out, int E, int nwaves) {
    const int l = threadIdx.x & 63;
    const int g = l >> 4;            // edge slot within a 4-edge chunk
    const int q = l & 15;            // j-group
    const int j0 = q << 2;
    const int wid = blockIdx.x * (blockDim.x >> 6) + (threadIdx.x >> 6);

    float4 wet[5], wlt[5];
#pragma unroll
    for (int k = 0; k < 5; ++k) {
        wet[k] = *(const float4*)&We1[(128 + k) * 64 + j0];
        wlt[k] = *(const float4*)&Wl1[(128 + k) * 64 + j0];
    }
    const float4 vbe1 = *(const float4*)&be1[j0];
    const float4 vwe2 = *(const float4*)&We2[j0];
    const float4 vbl1 = *(const float4*)&bl1[j0];
    const float4 vwl2 = *(const float4*)&Wl2[j0];
    const float vbe2 = be2[0], vbl2 = bl2[0];

    const int nch = (E + 3) >> 2;

#define KS(EK, K) \
    t4.x = fmaf(EK, wet[K].x, t4.x); t4.y = fmaf(EK, wet[K].y, t4.y); \
    t4.z = fmaf(EK, wet[K].z, t4.z); t4.w = fmaf(EK, wet[K].w, t4.w); \
    u4.x = fmaf(EK, wlt[K].x, u4.x); u4.y = fmaf(EK, wlt[K].y, u4.y); \
    u4.z = fmaf(EK, wlt[K].z, u4.z); u4.w = fmaf(EK, wlt[K].w, u4.w);

    for (int c = wid; c < nch; c += 2 * nwaves) {
        int c2 = c + nwaves;
        bool hasB = c2 < nch;
        int slotA = c * 4 + g;
        int slotB = hasB ? c2 * 4 + g : 0;
        bool actA = slotA < E;
        bool actB = hasB && slotB < E;
        // two independent chains: both csr, then both dstarr, then 4 gathers
        int2 seA = csr[actA ? slotA : 0];
        int2 seB = csr[actB ? slotB : 0];
        int dnA = dstarr[seA.y];
        int dnB = dstarr[seB.y];
        uint4 pwA = *(const uint4*)&ST32[(size_t)dnA * 128 + 64 + j0];
        uint4 swA = *(const uint4*)&ST32[(size_t)seA.x * 128 + j0];
        uint4 pwB = *(const uint4*)&ST32[(size_t)dnB * 128 + 64 + j0];
        uint4 swB = *(const uint4*)&ST32[(size_t)seB.x * 128 + j0];
        // per-quarter broadcast ef loads (same address within a quarter)
        const float* epA = ef + (size_t)seA.y * 5;
        const float* epB = ef + (size_t)seB.y * 5;
        float ekA0 = epA[0], ekA1 = epA[1], ekA2 = epA[2], ekA3 = epA[3], ekA4 = epA[4];
        float ekB0 = epB[0], ekB1 = epB[1], ekB2 = epB[2], ekB3 = epB[3], ekB4 = epB[4];

        // ---- chunk A ----
        {
            float4 t4 = {bflo(swA.x) + bflo(pwA.x) + vbe1.x,
                         bflo(swA.y) + bflo(pwA.y) + vbe1.y,
                         bflo(swA.z) + bflo(pwA.z) + vbe1.z,
                         bflo(swA.w) + bflo(pwA.w) + vbe1.w};
            float4 u4 = {bfhi(swA.x) + bfhi(pwA.x), bfhi(swA.y) + bfhi(pwA.y),
                         bfhi(swA.z) + bfhi(pwA.z), bfhi(swA.w) + bfhi(pwA.w)};
            KS(ekA0, 0) KS(ekA1, 1) KS(ekA2, 2) KS(ekA3, 3) KS(ekA4, 4)
            float z = fast_tanh(t4.x) * vwe2.x + fast_tanh(t4.y) * vwe2.y
                    + fast_tanh(t4.z) * vwe2.z + fast_tanh(t4.w) * vwe2.w;
            z = dpp_sum16(z);
            float w = fast_sigmoid(z + vbe2);
            float o = fmaxf(fmaf(w, u4.x, vbl1.x), 0.f) * vwl2.x
                    + fmaxf(fmaf(w, u4.y, vbl1.y), 0.f) * vwl2.y
                    + fmaxf(fmaf(w, u4.z, vbl1.z), 0.f) * vwl2.z
                    + fmaxf(fmaf(w, u4.w, vbl1.w), 0.f) * vwl2.w;
            o = dpp_sum16(o);
            if (q == 0 && actA) out[seA.y] = o + vbl2;
        }
        // ---- chunk B ----
        {
            float4 t4 = {bflo(swB.x) + bflo(pwB.x) + vbe1.x,
                         bflo(swB.y) + bflo(pwB.y) + vbe1.y,
                         bflo(swB.z) + bflo(pwB.z) + vbe1.z,
                         bflo(swB.w) + bflo(pwB.w) + vbe1.w};
            float4 u4 = {bfhi(swB.x) + bfhi(pwB.x), bfhi(swB.y) + bfhi(pwB.y),
                         bfhi(swB.z) + bfhi(pwB.z), bfhi(swB.w) + bfhi(pwB.w)};
            KS(ekB0, 0) KS(ekB1, 1) KS(ekB2, 2) KS(ekB3, 3) KS(ekB4, 4)
            float z = fast_tanh(t4.x) * vwe2.x + fast_tanh(t4.y) * vwe2.y
                    + fast_tanh(t4.z) * vwe2.z + fast_tanh(t4.w) * vwe2.w;
            z = dpp_sum16(z);
            float w = fast_sigmoid(z + vbe2);
            float o = fmaxf(fmaf(w, u4.x, vbl1.x), 0.f) * vwl2.x
                    + fmaxf(fmaf(w, u4.y, vbl1.y), 0.f) * vwl2.y
                    + fmaxf(fmaf(w, u4.z, vbl1.z), 0.f) * vwl2.z
                    + fmaxf(fmaf(w, u4.w, vbl1.w), 0.f) * vwl2.w;
            o = dpp_sum16(o);
            if (q == 0 && actB) out[seB.y] = o + vbl2;
        }
    }
#undef KS
}

extern "C" void kernel_launch(void* const* d_in, const int* in_sizes, int n_in,
                              void* d_out, int out_size, void* d_ws, size_t ws_size,
                              hipStream_t stream) {
    const float* nf  = (const float*)d_in[0];
    const float* ef  = (const float*)d_in[1];
    const int*   src = (const int*)d_in[2];
    const int*   dst = (const int*)d_in[3];
    const float* W1s = (const float*)d_in[4];
    const float* W1n = (const float*)d_in[5];
    const float* b1  = (const float*)d_in[6];
    const float* W2s = (const float*)d_in[7];
    const float* W2n = (const float*)d_in[8];
    const float* b2  = (const float*)d_in[9];
    const float* Wnp = (const float*)d_in[10];
    const float* bnp = (const float*)d_in[11];
    const float* We1 = (const float*)d_in[12];
    const float* be1 = (const float*)d_in[13];
    const float* We2 = (const float*)d_in[14];
    const float* be2 = (const float*)d_in[15];
    const float* Wl1 = (const float*)d_in[16];
    const float* bl1 = (const float*)d_in[17];
    const float* Wl2 = (const float*)d_in[18];
    const float* bl2 = (const float*)d_in[19];

    const int N = in_sizes[0] / 4;
    const int E = in_sizes[2];

    // ws layout (float units), peak ~274N = ~110 MB (proven budget ~128 MB):
    //  ST(bf16): [0, 128N)      written by node_mlp, read by edge_k
    //  ah1b:     [128N, 160N)   packed bf16 aggh1 (uint[32N])
    //  h1b:      [192N, 224N)   packed bf16 h1 (uint[32N])
    //  csr:      [224N, 256N)   int2[E]
    //  rank:     [256N, 272N)   int[E]
    //  deg:      [272N, 273N)   int[N]
    //  off:      [273N, 274N)+1 int[N+1]
    //  bsum:     off+N+1        int[512]
    float* wsf = (float*)d_ws;
    unsigned short* ST = (unsigned short*)wsf;
    unsigned* ah1b = (unsigned*)(wsf + (size_t)128 * N);
    unsigned* h1b  = (unsigned*)(wsf + (size_t)192 * N);
    int2* csr  = (int2*)(wsf + (size_t)224 * N);
    int*  rank = (int*)(wsf + (size_t)256 * N);
    int*  deg  = (int*)(wsf + (size_t)272 * N);
    int*  off  = deg + N;
    int*  bsum = off + N + 1;
    float* out = (float*)d_out;

    const int nblkN1 = (N + 255) / 256;
    const int nblkE  = (E + 255) / 256;
    const int nblkNw4 = (N + 3) / 4;      // 256-thread, 4 nodes (gatherh1)
    const int nblkN16 = (N + 15) / 16;    // 256-thread, 16 nodes (aggh1f)
    const int gemmx  = (N + 63) / 64;
    const int EDGE_BLOCKS = 3072;
    const int nwaves = EDGE_BLOCKS * 4;

    // CSR build: single atomic pass + scan + atomic-free fill
    hipMemsetAsync(deg, 0, (size_t)N * sizeof(int), stream);
    rank_k<<<nblkE, 256, 0, stream>>>(dst, deg, rank, E);
    scan1_k<<<nblkN1, 256, 0, stream>>>(deg, off, bsum, N);
    scan2_k<<<1, 512, 0, stream>>>(bsum, nblkN1);
    scan3_k<<<nblkN1, 256, 0, stream>>>(off, bsum, N, E);
    fill2_k<<<nblkE, 256, 0, stream>>>(src, dst, off, rank, csr, E);

    // layer 1 (fused aggregate + h1, bf16 out; quarter-wave per node)
    aggh1f_k<<<nblkN16, 256, 0, stream>>>(off, csr, nf, W1s, W1n, b1, h1b, N);

    // layer 2 gather (bf16 out, uint4, 16 rows in flight)
    gatherh1_k<<<nblkNw4, 256, 0, stream>>>(off, csr, (const uint4*)h1b,
                                            (uint4*)ah1b, N);

    // fused node MLP -> bf16 ST table
    node_mlp_k<<<gemmx, 256, 0, stream>>>(h1b, ah1b, W2s, W2n, b2,
                                          Wnp, bnp, We1, Wl1, ST, N);

    // per-edge scoring (balanced chunks, 2-way ILP, broadcast ef)
    edge_k<<<EDGE_BLOCKS, 256, 0, stream>>>(csr, dst, ef, (const unsigned*)ST,
                                            We1, be1, We2, be2, Wl1, bl1, Wl2, bl2,
                                            out, E, nwaves);
}